// Round 15
// baseline (1272.127 us; speedup 1.0000x reference)
//
#include <hip/hip_runtime.h>
#include <stdint.h>

typedef unsigned short u16;
typedef unsigned char u8;
typedef unsigned int u32;

#define LOG2E 1.4426950408889634f
#define LN2   0.6931471805599453f

typedef __attribute__((ext_vector_type(2))) float f32x2;

__device__ __forceinline__ float exp2_(float x){ return __builtin_amdgcn_exp2f(x); }
__device__ __forceinline__ float log2_(float x){ return __builtin_amdgcn_logf(x); }
__device__ __forceinline__ float bflo(u32 u){ return __uint_as_float(u << 16); }
__device__ __forceinline__ float bfhi(u32 u){ return __uint_as_float(u & 0xffff0000u); }
__device__ __forceinline__ u16 f2bf(float f){
  u32 u = __float_as_uint(f);
  return (u16)((u + 0x7fffu + ((u >> 16) & 1u)) >> 16);
}
// pack two f32 -> two bf16 in one u32 (1 VALU op on gfx950)
__device__ __forceinline__ u32 pkbf(float lo, float hi){
  u32 r; asm("v_cvt_pk_bf16_f32 %0, %1, %2" : "=v"(r) : "v"(lo), "v"(hi)); return r;
}
// bool input read: stride 1 (u8 bools) or 4 (int32 bools, LE low byte)
__device__ __forceinline__ int rdmask(const u8* p, int i, int st){ return (int)p[(size_t)i * st]; }

// ---------------- detect bool dtype: crf_mask[0,:] is all-true ----------------
__global__ void k_detect(const u32* __restrict__ cmask, int* __restrict__ flags) {
  flags[0] = (cmask[0] == 0x01010101u) ? 1 : 4;
}

// ---------------- normalize rows (txt & img) to bf16 ----------------
__global__ __launch_bounds__(256) void k_normalize(const float* __restrict__ txt,
                                                   const float* __restrict__ img,
                                                   u16* __restrict__ xh, u16* __restrict__ yh) {
  int row = blockIdx.x * 4 + (threadIdx.x >> 6);
  int l = threadIdx.x & 63;
  const float* src; u16* dst;
  if (row < 32768) { src = txt + (size_t)row * 768; dst = xh + (size_t)row * 768; }
  else { int r2 = row - 32768; src = img + (size_t)r2 * 768; dst = yh + (size_t)r2 * 768; }
  float v[12]; float ss = 0.f;
  #pragma unroll
  for (int s = 0; s < 12; ++s) { v[s] = src[l + (s << 6)]; ss = fmaf(v[s], v[s], ss); }
  #pragma unroll
  for (int off = 32; off; off >>= 1) ss += __shfl_xor(ss, off);
  float sc = 1.0f / fmaxf(sqrtf(ss), 1e-5f);
  #pragma unroll
  for (int s = 0; s < 12; ++s) dst[l + (s << 6)] = f2bf(v[s] * sc);
}

// ---------------- cost matrix GEMM + (hidden) CRF (verbatim R13/R14, passing) --------
typedef __attribute__((ext_vector_type(8))) short short8;
typedef __attribute__((ext_vector_type(4))) float f32x4;

__global__ __launch_bounds__(256) void k_gemm_crf(const u16* __restrict__ xh, const u16* __restrict__ yh,
                                                  const u8* __restrict__ xpad, const u8* __restrict__ ypad,
                                                  const int* __restrict__ flags,
                                                  u16* __restrict__ Ct2,
                                                  const float* __restrict__ emis, const int* __restrict__ tags,
                                                  const u8* __restrict__ mask,
                                                  const float* __restrict__ startT, const float* __restrict__ endT,
                                                  const float* __restrict__ trans, float* __restrict__ llh) {
  __shared__ u16 As[128 * 64];
  __shared__ u16 Bs[128 * 64];
  __shared__ float tr[441];
  int st = flags[0];
  int bt = blockIdx.x;
  int tid = threadIdx.x;

  if (bt >= 1024) {
    // ---------------- CRF branch ----------------
    int b = bt - 1024;
    for (int i = tid; i < 441; i += 256) tr[i] = trans[i];
    __syncthreads();
    if (tid >= 64) return;
    int k = tid;
    float accs = 0.f; int cnt = 0;
    for (int t = k; t < 512; t += 64) {
      int mt = rdmask(mask, (t << 6) + b, st);
      cnt += mt;
      int tg = tags[(t << 6) + b];
      if (t == 0) {
        accs += startT[tg] + emis[(size_t)b * 21 + tg];
      } else if (mt) {
        int tgp = tags[((t - 1) << 6) + b];
        accs += tr[tgp * 21 + tg] + emis[((size_t)((t << 6) + b)) * 21 + tg];
      }
    }
    #pragma unroll
    for (int off = 32; off; off >>= 1) { accs += __shfl_down(accs, off); cnt += __shfl_down(cnt, off); }
    float numer = 0.f;
    if (k == 0) {
      int last = tags[((cnt - 1) << 6) + b];
      numer = accs + endT[last];
    }
    int kc = (k < 21) ? k : 20;
    float s = startT[kc] + emis[(size_t)b * 21 + kc];
    for (int t = 1; t < 512; ++t) {
      float z[21];
      float zmax = -3.0e38f;
      #pragma unroll
      for (int j = 0; j < 21; ++j) {
        float sj = __shfl(s, j);
        z[j] = sj + tr[j * 21 + kc];
        zmax = fmaxf(zmax, z[j]);
      }
      float sum = 0.f;
      #pragma unroll
      for (int j = 0; j < 21; ++j) sum += exp2_((z[j] - zmax) * LOG2E);
      float ns = zmax + log2_(sum) * LN2 + emis[((size_t)((t << 6) + b)) * 21 + kc];
      s = rdmask(mask, (t << 6) + b, st) ? ns : s;
    }
    float f = (k < 21) ? (s + endT[kc]) : -3.0e38f;
    float m = f;
    #pragma unroll
    for (int off = 32; off; off >>= 1) m = fmaxf(m, __shfl_xor(m, off));
    float sum = (k < 21) ? exp2_((f - m) * LOG2E) : 0.f;
    #pragma unroll
    for (int off = 32; off; off >>= 1) sum += __shfl_xor(sum, off);
    float denom = m + log2_(sum) * LN2;
    if (k == 0) llh[b] = numer - denom;
    return;
  }

  // ---------------- GEMM branch ----------------
  int b = bt >> 4;
  int tile = bt & 15;
  int tn = tile >> 2, tm = tile & 3;
  const u16* Ab = yh + ((size_t)b * 512 + tn * 128) * 768;
  const u16* Bb = xh + ((size_t)b * 512 + tm * 128) * 768;
  int w = tid >> 6, l = tid & 63;
  int wr = (w >> 1) << 6, wc = (w & 1) << 6;
  f32x4 acc[4][4] = {};
  for (int k0 = 0; k0 < 768; k0 += 64) {
    #pragma unroll
    for (int q = 0; q < 4; ++q) {
      int slot = (q << 8) + tid;
      int row = slot >> 3, col = (slot & 7) << 3;
      uint4 va = *(const uint4*)(Ab + row * 768 + k0 + col);
      uint4 vb = *(const uint4*)(Bb + row * 768 + k0 + col);
      *(uint4*)((char*)As + slot * 16) = va;
      *(uint4*)((char*)Bs + slot * 16) = vb;
    }
    __syncthreads();
    #pragma unroll
    for (int kk = 0; kk < 64; kk += 32) {
      int cb = (kk + ((l >> 4) << 3)) * 2;
      short8 a[4], bb[4];
      #pragma unroll
      for (int i = 0; i < 4; ++i)
        a[i] = *(const short8*)((const char*)As + (wr + (i << 4) + (l & 15)) * 128 + cb);
      #pragma unroll
      for (int j = 0; j < 4; ++j)
        bb[j] = *(const short8*)((const char*)Bs + (wc + (j << 4) + (l & 15)) * 128 + cb);
      #pragma unroll
      for (int i = 0; i < 4; ++i)
        #pragma unroll
        for (int j = 0; j < 4; ++j)
          acc[i][j] = __builtin_amdgcn_mfma_f32_16x16x32_bf16(a[i], bb[j], acc[i][j], 0, 0, 0);
    }
    __syncthreads();
  }
  int n0 = (tn << 7) + wr, m0 = (tm << 7) + wc;
  #pragma unroll
  for (int i = 0; i < 4; ++i) {
    #pragma unroll
    for (int j = 0; j < 4; ++j) {
      int m = m0 + (j << 4) + (l & 15);
      int xpm = rdmask(xpad, b * 512 + m, st);
      #pragma unroll
      for (int r = 0; r < 4; ++r) {
        int n = n0 + (i << 4) + ((l >> 4) << 2) + r;
        float v = 2.8853901f * (1.0f - acc[i][j][r]);
        if (xpm | rdmask(ypad, b * 512 + n, st)) v = 30000.0f;
        Ct2[((size_t)(b * 512 + n) << 9) + m] = f2bf(v);
      }
    }
  }
}

// ---------------- cross-block per-batch barrier (agent-scope) ----------------
__device__ __forceinline__ void batch_barrier(int* cnt, int target) {
  __syncthreads();
  if (threadIdx.x == 0) {
    __hip_atomic_fetch_add(cnt, 1, __ATOMIC_RELEASE, __HIP_MEMORY_SCOPE_AGENT);
    while (__hip_atomic_load(cnt, __ATOMIC_ACQUIRE, __HIP_MEMORY_SCOPE_AGENT) < target)
      __builtin_amdgcn_s_sleep(1);
  }
  __syncthreads();
}

// ---------------- IPOT: 8 blocks/batch x 1024 thr (R4-validated protocol) ----
// b = bid>>3, p = bid&7 (CONTIGUOUS groups -- deadlock-free at any occupancy:
// blocks dispatch in bid order; the oldest unfinished group's 8 members are
// always resident, complete, free slots -- R4 empirically validated this at
// grid 512 x 1024 thr with the same aliased scratch + cross-XCD barrier).
// Inner math = R14-validated: A fp8-e4m3 in LDS, T packed bf16 in VGPRs.
// Each block owns 64 rows; wave w owns rows [p*64+w*4, +4); lane l cols [l*8,+8).
// Tp[16] packed + q[8] transient ~= 50 live regs < 64 budget (no spill).
// LDS ~54.5KB -> 2 blocks/CU co-residency possible (32 waves/CU); fused
// sweep1+2 (colpart uses q while still f32) removes sweep2's unpacking.
__global__ __launch_bounds__(1024)
void k_ipot8f8(const u16* __restrict__ Ct2,
               const u8* __restrict__ xpad, const u8* __restrict__ ypad,
               const int* __restrict__ flags,
               int* __restrict__ gcount, float* __restrict__ c_part,
               float* __restrict__ fin_part,
               float* __restrict__ ot) {
  __shared__ __align__(16) u32  A_l[64 * 128];       // 32768 B (fp8, 512 cols/row)
  __shared__ __align__(16) float cpart[8][512];      // 16384 B
  __shared__ __align__(16) float sig[512];           //  2048 B
  __shared__ __align__(16) float xmk[512];           //  2048 B
  __shared__ __align__(16) float ymk[512];           //  2048 B
  __shared__ float redw[16];
  __shared__ int cnti[2];

  int bid = blockIdx.x;
  int b = bid >> 3, p = bid & 7;                // contiguous: batch b = bids [8b, 8b+8)
  int tid = threadIdx.x;
  int w = tid >> 6, l = tid & 63;               // w in 0..15
  int st = flags[0];

  if (tid < 2) cnti[tid] = 0;
  __syncthreads();
  if (tid < 512) {
    int xp = rdmask(xpad, (b << 9) + tid, st) ? 1 : 0;
    int yp = rdmask(ypad, (b << 9) + tid, st) ? 1 : 0;
    xmk[tid] = xp ? 1e4f : 0.f;
    ymk[tid] = yp ? 1e4f : 0.f;
    atomicAdd(&cnti[0], 1 - xp);
    atomicAdd(&cnti[1], 1 - yp);
  }
  __syncthreads();
  float xl = (float)cnti[0], yl = (float)cnti[1];
  if (tid < 512) sig[tid] = (xmk[tid] > 0.f) ? 0.f : (1.0f / xl);

  const int base_n = p << 6;
  const int row0 = (w << 2);                    // local row of this wave (4 rows)
  const u16* Cb = Ct2 + ((size_t)(b * 512 + base_n) << 9);
  int* cnt_b = gcount + (b << 6);
  float* cp_b = c_part + (size_t)b * 8192;      // 2 parities * 8 parts * 512

  // ---- precompute A = exp2(-Ct2) into LDS (fp8), init T = 1 (packed bf16) ----
  u32 Tp[16];
  #pragma unroll
  for (int r = 0; r < 4; ++r) {
    const uint4 cv = *(const uint4*)(Cb + (size_t)(row0 + r) * 512 + (l << 3));
    float a0 = exp2_(-bflo(cv.x)), a1 = exp2_(-bfhi(cv.x));
    float a2 = exp2_(-bflo(cv.y)), a3 = exp2_(-bfhi(cv.y));
    float a4 = exp2_(-bflo(cv.z)), a5 = exp2_(-bfhi(cv.z));
    float a6 = exp2_(-bflo(cv.w)), a7 = exp2_(-bfhi(cv.w));
    u32 w0 = (u32)__builtin_amdgcn_cvt_pk_fp8_f32(a0, a1, 0, false);
    w0 = (u32)__builtin_amdgcn_cvt_pk_fp8_f32(a2, a3, (int)w0, true);
    u32 w1 = (u32)__builtin_amdgcn_cvt_pk_fp8_f32(a4, a5, 0, false);
    w1 = (u32)__builtin_amdgcn_cvt_pk_fp8_f32(a6, a7, (int)w1, true);
    uint2 wv; wv.x = w0; wv.y = w1;
    *(uint2*)(A_l + (row0 + r) * 128 + (l << 1)) = wv;
    Tp[r * 4 + 0] = 0x3F803F80u;  // (1.0bf16, 1.0bf16)
    Tp[r * 4 + 1] = 0x3F803F80u;
    Tp[r * 4 + 2] = 0x3F803F80u;
    Tp[r * 4 + 3] = 0x3F803F80u;
  }
  __syncthreads();

  for (int it = 1; it <= 50; ++it) {
    int par = it & 1;
    float dl[4];
    float cp[8] = {0.f,0.f,0.f,0.f,0.f,0.f,0.f,0.f};
    {
      // sigma for my 8 cols
      float sg[8];
      const float4* ps = (const float4*)&sig[l << 3];
      float4 s0 = ps[0], s1 = ps[1];
      sg[0]=s0.x; sg[1]=s0.y; sg[2]=s0.z; sg[3]=s0.w;
      sg[4]=s1.x; sg[5]=s1.y; sg[6]=s1.z; sg[7]=s1.w;
      // ---- fused sweep1+2 per row: Q=A*T (repack), rowsum->delta, colpart += delta*Q ----
      #pragma unroll
      for (int r = 0; r < 4; ++r) {
        const uint2 av = *(const uint2*)(A_l + (row0 + r) * 128 + (l << 1));
        f32x2 a01 = __builtin_amdgcn_cvt_pk_f32_fp8((int)av.x, false);
        f32x2 a23 = __builtin_amdgcn_cvt_pk_f32_fp8((int)av.x, true);
        f32x2 a45 = __builtin_amdgcn_cvt_pk_f32_fp8((int)av.y, false);
        f32x2 a67 = __builtin_amdgcn_cvt_pk_f32_fp8((int)av.y, true);
        float q[8];
        float acc = 0.f;
        { u32 tw = Tp[r*4+0]; q[0] = a01.x*bflo(tw); q[1] = a01.y*bfhi(tw);
          Tp[r*4+0] = pkbf(q[0],q[1]); acc = fmaf(q[0],sg[0],acc); acc = fmaf(q[1],sg[1],acc); }
        { u32 tw = Tp[r*4+1]; q[2] = a23.x*bflo(tw); q[3] = a23.y*bfhi(tw);
          Tp[r*4+1] = pkbf(q[2],q[3]); acc = fmaf(q[2],sg[2],acc); acc = fmaf(q[3],sg[3],acc); }
        { u32 tw = Tp[r*4+2]; q[4] = a45.x*bflo(tw); q[5] = a45.y*bfhi(tw);
          Tp[r*4+2] = pkbf(q[4],q[5]); acc = fmaf(q[4],sg[4],acc); acc = fmaf(q[5],sg[5],acc); }
        { u32 tw = Tp[r*4+3]; q[6] = a67.x*bflo(tw); q[7] = a67.y*bfhi(tw);
          Tp[r*4+3] = pkbf(q[6],q[7]); acc = fmaf(q[6],sg[6],acc); acc = fmaf(q[7],sg[7],acc); }
        #pragma unroll
        for (int off = 32; off; off >>= 1) acc += __shfl_xor(acc, off);
        float d = 1.0f / fmaf(yl, acc, ymk[base_n + row0 + r]);
        dl[r] = d;
        #pragma unroll
        for (int c = 0; c < 8; ++c) cp[c] = fmaf(d, q[c], cp[c]);
      }
    }
    // ---- 8-slot colsum tree in LDS (2 rounds, deterministic) ----
    {
      float4 v0, v1;
      v0.x=cp[0]; v0.y=cp[1]; v0.z=cp[2]; v0.w=cp[3];
      v1.x=cp[4]; v1.y=cp[5]; v1.z=cp[6]; v1.w=cp[7];
      float4* dst = (float4*)&cpart[w & 7][l << 3];
      if (w < 8) { dst[0] = v0; dst[1] = v1; }
      __syncthreads();
      if (w >= 8) {
        float4 o0 = dst[0], o1 = dst[1];
        o0.x+=v0.x; o0.y+=v0.y; o0.z+=v0.z; o0.w+=v0.w;
        o1.x+=v1.x; o1.y+=v1.y; o1.z+=v1.z; o1.w+=v1.w;
        dst[0] = o0; dst[1] = o1;
      }
      __syncthreads();
    }
    if (tid < 512) {
      float s = 0.f;
      #pragma unroll
      for (int k = 0; k < 8; ++k) s += cpart[k][tid];
      __hip_atomic_store(&cp_b[(par << 12) + (p << 9) + tid], s, __ATOMIC_RELAXED, __HIP_MEMORY_SCOPE_AGENT);
    }
    batch_barrier(&cnt_b[it - 1], 8);
    if (tid < 512) {
      const float* basep = cp_b + (par << 12);
      float s = 0.f;
      #pragma unroll
      for (int pp = 0; pp < 8; ++pp)
        s += __hip_atomic_load(&basep[(pp << 9) + tid], __ATOMIC_RELAXED, __HIP_MEMORY_SCOPE_AGENT);
      sig[tid] = 1.0f / fmaf(xl, s, xmk[tid]);
    }
    __syncthreads();
    // ---- sweep3: T = Q * delta * sigma' ----
    {
      float sg[8];
      const float4* ps = (const float4*)&sig[l << 3];
      float4 s0 = ps[0], s1 = ps[1];
      sg[0]=s0.x; sg[1]=s0.y; sg[2]=s0.z; sg[3]=s0.w;
      sg[4]=s1.x; sg[5]=s1.y; sg[6]=s1.z; sg[7]=s1.w;
      #pragma unroll
      for (int r = 0; r < 4; ++r) {
        float d = dl[r];
        { u32 tw = Tp[r*4+0]; Tp[r*4+0] = pkbf(bflo(tw)*d*sg[0], bfhi(tw)*d*sg[1]); }
        { u32 tw = Tp[r*4+1]; Tp[r*4+1] = pkbf(bflo(tw)*d*sg[2], bfhi(tw)*d*sg[3]); }
        { u32 tw = Tp[r*4+2]; Tp[r*4+2] = pkbf(bflo(tw)*d*sg[4], bfhi(tw)*d*sg[5]); }
        { u32 tw = Tp[r*4+3]; Tp[r*4+3] = pkbf(bflo(tw)*d*sg[6], bfhi(tw)*d*sg[7]); }
      }
    }
  }

  // ---- final: partial dist = sum Ct2*T (masked: Ct2=3e4 but T=0 exactly) ----
  float accT = 0.f;
  #pragma unroll
  for (int r = 0; r < 4; ++r) {
    const uint4 cv = *(const uint4*)(Cb + (size_t)(row0 + r) * 512 + (l << 3));
    { u32 tw = Tp[r*4+0]; accT = fmaf(bflo(cv.x), bflo(tw), accT); accT = fmaf(bfhi(cv.x), bfhi(tw), accT); }
    { u32 tw = Tp[r*4+1]; accT = fmaf(bflo(cv.y), bflo(tw), accT); accT = fmaf(bfhi(cv.y), bfhi(tw), accT); }
    { u32 tw = Tp[r*4+2]; accT = fmaf(bflo(cv.z), bflo(tw), accT); accT = fmaf(bfhi(cv.z), bfhi(tw), accT); }
    { u32 tw = Tp[r*4+3]; accT = fmaf(bflo(cv.w), bflo(tw), accT); accT = fmaf(bfhi(cv.w), bfhi(tw), accT); }
  }
  #pragma unroll
  for (int off = 32; off; off >>= 1) accT += __shfl_xor(accT, off);
  if (l == 0) redw[w] = accT;
  __syncthreads();
  if (tid == 0) {
    float s = 0.f;
    #pragma unroll
    for (int ww = 0; ww < 16; ++ww) s += redw[ww];
    __hip_atomic_store(&fin_part[(b << 3) + p], s, __ATOMIC_RELAXED, __HIP_MEMORY_SCOPE_AGENT);
  }
  batch_barrier(&cnt_b[50], 8);
  if (p == 0 && tid == 0) {
    float s = 0.f;
    #pragma unroll
    for (int pp = 0; pp < 8; ++pp)
      s += __hip_atomic_load(&fin_part[(b << 3) + pp], __ATOMIC_RELAXED, __HIP_MEMORY_SCOPE_AGENT);
    ot[b] = s * 0.34657359f;  // beta * ln2  (Ct2 is in log2 units)
  }
}

// ---------------- finalize: out = sum_b (ot[b] - llh[b]) ----------------
__global__ __launch_bounds__(64) void k_finalize(const float* __restrict__ llh, const float* __restrict__ ot,
                                                 float* __restrict__ out) {
  int l = threadIdx.x;
  float v = ot[l] - llh[l];
  #pragma unroll
  for (int off = 32; off; off >>= 1) v += __shfl_down(v, off);
  if (l == 0) out[0] = v;
}

extern "C" void kernel_launch(void* const* d_in, const int* in_sizes, int n_in,
                              void* d_out, int out_size, void* d_ws, size_t ws_size,
                              hipStream_t stream) {
  const float* emis  = (const float*)d_in[0];
  const float* txt   = (const float*)d_in[1];
  const float* img   = (const float*)d_in[2];
  const float* startT= (const float*)d_in[3];
  const float* endT  = (const float*)d_in[4];
  const float* trans = (const float*)d_in[5];
  const int*  tags   = (const int*)d_in[6];
  const u8* cmask = (const u8*)d_in[7];
  const u8* xpad  = (const u8*)d_in[8];
  const u8* ypad  = (const u8*)d_in[9];
  char* wsb = (char*)d_ws;
  u16* xh  = (u16*)wsb;                          // 50331648 B (dead after gemm)
  u16* yh  = (u16*)(wsb + 50331648ll);           // 50331648 B (dead after gemm)
  u16* Ct2 = (u16*)(wsb + 100663296ll);          // 33554432 B
  float* ot    = (float*)(wsb + 134217728ll);    // 64 f32
  float* llh   = ot + 64;                        // 64 f32
  int*  flags  = (int*)(llh + 64);
  // ipot scratch aliases the dead xh region (memset AFTER gemm) -- R4-validated layout:
  int*  gcount  = (int*)wsb;                     // 64*64 ints = 16384 B
  float* c_part = (float*)(wsb + 16384ll);       // 64*2*8*512 f32 = 2 MB
  float* fin_part=(float*)(wsb + 16384ll + 2097152ll); // 64*8 f32
  float* out = (float*)d_out;

  hipLaunchKernelGGL(k_detect, dim3(1), dim3(1), 0, stream, (const u32*)cmask, flags);
  hipLaunchKernelGGL(k_normalize, dim3(16384), dim3(256), 0, stream, txt, img, xh, yh);
  hipLaunchKernelGGL(k_gemm_crf, dim3(1088), dim3(256), 0, stream, xh, yh, xpad, ypad, flags, Ct2,
                     emis, tags, cmask, startT, endT, trans, llh);
  hipMemsetAsync(gcount, 0, 64 * 64 * sizeof(int), stream);
  hipLaunchKernelGGL(k_ipot8f8, dim3(512), dim3(1024), 0, stream,
                     Ct2, xpad, ypad, flags, gcount, c_part, fin_part, ot);
  hipLaunchKernelGGL(k_finalize, dim3(1), dim3(64), 0, stream, llh, ot, out);
}

// Round 16
// 1083.665 us; speedup vs baseline: 1.1739x; 1.1739x over previous
//
#include <hip/hip_runtime.h>
#include <stdint.h>

typedef unsigned short u16;
typedef unsigned char u8;
typedef unsigned int u32;

#define LOG2E 1.4426950408889634f
#define LN2   0.6931471805599453f

typedef __attribute__((ext_vector_type(2))) float f32x2;

__device__ __forceinline__ float exp2_(float x){ return __builtin_amdgcn_exp2f(x); }
__device__ __forceinline__ float log2_(float x){ return __builtin_amdgcn_logf(x); }
__device__ __forceinline__ float bflo(u32 u){ return __uint_as_float(u << 16); }
__device__ __forceinline__ float bfhi(u32 u){ return __uint_as_float(u & 0xffff0000u); }
__device__ __forceinline__ u16 f2bf(float f){
  u32 u = __float_as_uint(f);
  return (u16)((u + 0x7fffu + ((u >> 16) & 1u)) >> 16);
}
// pack two f32 -> two bf16 in one u32 (1 VALU op on gfx950)
__device__ __forceinline__ u32 pkbf(float lo, float hi){
  u32 r; asm("v_cvt_pk_bf16_f32 %0, %1, %2" : "=v"(r) : "v"(lo), "v"(hi)); return r;
}
// bool input read: stride 1 (u8 bools) or 4 (int32 bools, LE low byte)
__device__ __forceinline__ int rdmask(const u8* p, int i, int st){ return (int)p[(size_t)i * st]; }

// ---------------- detect bool dtype: crf_mask[0,:] is all-true ----------------
__global__ void k_detect(const u32* __restrict__ cmask, int* __restrict__ flags) {
  flags[0] = (cmask[0] == 0x01010101u) ? 1 : 4;
}

// ---------------- normalize rows (txt & img) to bf16 ----------------
__global__ __launch_bounds__(256) void k_normalize(const float* __restrict__ txt,
                                                   const float* __restrict__ img,
                                                   u16* __restrict__ xh, u16* __restrict__ yh) {
  int row = blockIdx.x * 4 + (threadIdx.x >> 6);
  int l = threadIdx.x & 63;
  const float* src; u16* dst;
  if (row < 32768) { src = txt + (size_t)row * 768; dst = xh + (size_t)row * 768; }
  else { int r2 = row - 32768; src = img + (size_t)r2 * 768; dst = yh + (size_t)r2 * 768; }
  float v[12]; float ss = 0.f;
  #pragma unroll
  for (int s = 0; s < 12; ++s) { v[s] = src[l + (s << 6)]; ss = fmaf(v[s], v[s], ss); }
  #pragma unroll
  for (int off = 32; off; off >>= 1) ss += __shfl_xor(ss, off);
  float sc = 1.0f / fmaxf(sqrtf(ss), 1e-5f);
  #pragma unroll
  for (int s = 0; s < 12; ++s) dst[l + (s << 6)] = f2bf(v[s] * sc);
}

// ---------------- cost matrix GEMM + (hidden) CRF (verbatim R13/R14, passing) --------
typedef __attribute__((ext_vector_type(8))) short short8;
typedef __attribute__((ext_vector_type(4))) float f32x4;

__global__ __launch_bounds__(256) void k_gemm_crf(const u16* __restrict__ xh, const u16* __restrict__ yh,
                                                  const u8* __restrict__ xpad, const u8* __restrict__ ypad,
                                                  const int* __restrict__ flags,
                                                  u16* __restrict__ Ct2,
                                                  const float* __restrict__ emis, const int* __restrict__ tags,
                                                  const u8* __restrict__ mask,
                                                  const float* __restrict__ startT, const float* __restrict__ endT,
                                                  const float* __restrict__ trans, float* __restrict__ llh) {
  __shared__ u16 As[128 * 64];
  __shared__ u16 Bs[128 * 64];
  __shared__ float tr[441];
  int st = flags[0];
  int bt = blockIdx.x;
  int tid = threadIdx.x;

  if (bt >= 1024) {
    // ---------------- CRF branch ----------------
    int b = bt - 1024;
    for (int i = tid; i < 441; i += 256) tr[i] = trans[i];
    __syncthreads();
    if (tid >= 64) return;
    int k = tid;
    float accs = 0.f; int cnt = 0;
    for (int t = k; t < 512; t += 64) {
      int mt = rdmask(mask, (t << 6) + b, st);
      cnt += mt;
      int tg = tags[(t << 6) + b];
      if (t == 0) {
        accs += startT[tg] + emis[(size_t)b * 21 + tg];
      } else if (mt) {
        int tgp = tags[((t - 1) << 6) + b];
        accs += tr[tgp * 21 + tg] + emis[((size_t)((t << 6) + b)) * 21 + tg];
      }
    }
    #pragma unroll
    for (int off = 32; off; off >>= 1) { accs += __shfl_down(accs, off); cnt += __shfl_down(cnt, off); }
    float numer = 0.f;
    if (k == 0) {
      int last = tags[((cnt - 1) << 6) + b];
      numer = accs + endT[last];
    }
    int kc = (k < 21) ? k : 20;
    float s = startT[kc] + emis[(size_t)b * 21 + kc];
    for (int t = 1; t < 512; ++t) {
      float z[21];
      float zmax = -3.0e38f;
      #pragma unroll
      for (int j = 0; j < 21; ++j) {
        float sj = __shfl(s, j);
        z[j] = sj + tr[j * 21 + kc];
        zmax = fmaxf(zmax, z[j]);
      }
      float sum = 0.f;
      #pragma unroll
      for (int j = 0; j < 21; ++j) sum += exp2_((z[j] - zmax) * LOG2E);
      float ns = zmax + log2_(sum) * LN2 + emis[((size_t)((t << 6) + b)) * 21 + kc];
      s = rdmask(mask, (t << 6) + b, st) ? ns : s;
    }
    float f = (k < 21) ? (s + endT[kc]) : -3.0e38f;
    float m = f;
    #pragma unroll
    for (int off = 32; off; off >>= 1) m = fmaxf(m, __shfl_xor(m, off));
    float sum = (k < 21) ? exp2_((f - m) * LOG2E) : 0.f;
    #pragma unroll
    for (int off = 32; off; off >>= 1) sum += __shfl_xor(sum, off);
    float denom = m + log2_(sum) * LN2;
    if (k == 0) llh[b] = numer - denom;
    return;
  }

  // ---------------- GEMM branch ----------------
  int b = bt >> 4;
  int tile = bt & 15;
  int tn = tile >> 2, tm = tile & 3;
  const u16* Ab = yh + ((size_t)b * 512 + tn * 128) * 768;
  const u16* Bb = xh + ((size_t)b * 512 + tm * 128) * 768;
  int w = tid >> 6, l = tid & 63;
  int wr = (w >> 1) << 6, wc = (w & 1) << 6;
  f32x4 acc[4][4] = {};
  for (int k0 = 0; k0 < 768; k0 += 64) {
    #pragma unroll
    for (int q = 0; q < 4; ++q) {
      int slot = (q << 8) + tid;
      int row = slot >> 3, col = (slot & 7) << 3;
      uint4 va = *(const uint4*)(Ab + row * 768 + k0 + col);
      uint4 vb = *(const uint4*)(Bb + row * 768 + k0 + col);
      *(uint4*)((char*)As + slot * 16) = va;
      *(uint4*)((char*)Bs + slot * 16) = vb;
    }
    __syncthreads();
    #pragma unroll
    for (int kk = 0; kk < 64; kk += 32) {
      int cb = (kk + ((l >> 4) << 3)) * 2;
      short8 a[4], bb[4];
      #pragma unroll
      for (int i = 0; i < 4; ++i)
        a[i] = *(const short8*)((const char*)As + (wr + (i << 4) + (l & 15)) * 128 + cb);
      #pragma unroll
      for (int j = 0; j < 4; ++j)
        bb[j] = *(const short8*)((const char*)Bs + (wc + (j << 4) + (l & 15)) * 128 + cb);
      #pragma unroll
      for (int i = 0; i < 4; ++i)
        #pragma unroll
        for (int j = 0; j < 4; ++j)
          acc[i][j] = __builtin_amdgcn_mfma_f32_16x16x32_bf16(a[i], bb[j], acc[i][j], 0, 0, 0);
    }
    __syncthreads();
  }
  int n0 = (tn << 7) + wr, m0 = (tm << 7) + wc;
  #pragma unroll
  for (int i = 0; i < 4; ++i) {
    #pragma unroll
    for (int j = 0; j < 4; ++j) {
      int m = m0 + (j << 4) + (l & 15);
      int xpm = rdmask(xpad, b * 512 + m, st);
      #pragma unroll
      for (int r = 0; r < 4; ++r) {
        int n = n0 + (i << 4) + ((l >> 4) << 2) + r;
        float v = 2.8853901f * (1.0f - acc[i][j][r]);
        if (xpm | rdmask(ypad, b * 512 + n, st)) v = 30000.0f;
        Ct2[((size_t)(b * 512 + n) << 9) + m] = f2bf(v);
      }
    }
  }
}

// ---------------- cross-block per-batch barrier (agent-scope) ----------------
__device__ __forceinline__ void batch_barrier(int* cnt, int target) {
  __syncthreads();
  if (threadIdx.x == 0) {
    __hip_atomic_fetch_add(cnt, 1, __ATOMIC_RELEASE, __HIP_MEMORY_SCOPE_AGENT);
    while (__hip_atomic_load(cnt, __ATOMIC_ACQUIRE, __HIP_MEMORY_SCOPE_AGENT) < target)
      __builtin_amdgcn_s_sleep(1);
  }
  __syncthreads();
}

// ---------------- IPOT: 8 blocks/batch x 1024 thr, XCD-colocated stride groups ----
// Mapping: b = ((bid>>6)<<3)|(bid&7), p = (bid>>3)&7. Batch b's bids are
// (b>>3)*64 + 8j + (b&7), j=0..7: all == b (mod 8) -> SAME XCD under round-robin
// dispatch (R5/R14 co-location lesson; R15's contiguous bids scattered each group
// over 8 XCDs -> 237MB cross-XCD exchange traffic, +455us), and consecutive slots
// in that XCD's queue -> oldest unfinished group always fits the 32-CU window ->
// deadlock-free at any occupancy (R4-style induction, per-XCD).
// A lives in REGISTERS (Af8[8]: 4 rows x 8 cols fp8 per thread) -- no A_l; LDS
// drops 55.8->22.6KB so co-residency isn't LDS-limited. T packed bf16 (Tp[16]).
// Peak live ~58 regs <= 64 budget (watch WRITE_SIZE for spill).
__global__ __launch_bounds__(1024)
void k_ipot8f8(const u16* __restrict__ Ct2,
               const u8* __restrict__ xpad, const u8* __restrict__ ypad,
               const int* __restrict__ flags,
               int* __restrict__ gcount, float* __restrict__ c_part,
               float* __restrict__ fin_part,
               float* __restrict__ ot) {
  __shared__ __align__(16) float cpart[8][512];      // 16384 B
  __shared__ __align__(16) float sig[512];           //  2048 B
  __shared__ __align__(16) float xmk[512];           //  2048 B
  __shared__ __align__(16) float ymk[512];           //  2048 B
  __shared__ float redw[16];
  __shared__ int cnti[2];

  int bid = blockIdx.x;
  int b = ((bid >> 6) << 3) | (bid & 7);        // XCD-colocated stride groups
  int p = (bid >> 3) & 7;
  int tid = threadIdx.x;
  int w = tid >> 6, l = tid & 63;               // w in 0..15
  int st = flags[0];

  if (tid < 2) cnti[tid] = 0;
  __syncthreads();
  if (tid < 512) {
    int xp = rdmask(xpad, (b << 9) + tid, st) ? 1 : 0;
    int yp = rdmask(ypad, (b << 9) + tid, st) ? 1 : 0;
    xmk[tid] = xp ? 1e4f : 0.f;
    ymk[tid] = yp ? 1e4f : 0.f;
    atomicAdd(&cnti[0], 1 - xp);
    atomicAdd(&cnti[1], 1 - yp);
  }
  __syncthreads();
  float xl = (float)cnti[0], yl = (float)cnti[1];
  if (tid < 512) sig[tid] = (xmk[tid] > 0.f) ? 0.f : (1.0f / xl);
  __syncthreads();

  const int base_n = p << 6;
  const int row0 = (w << 2);                    // local row of this wave (4 rows)
  const u16* Cb = Ct2 + ((size_t)(b * 512 + base_n) << 9);
  int* cnt_b = gcount + (b << 6);
  float* cp_b = c_part + (size_t)b * 8192;      // 2 parities * 8 parts * 512

  // ---- precompute A = exp2(-Ct2) into REGISTERS (fp8), init T = 1 (packed bf16) ----
  u32 Af8[8];
  u32 Tp[16];
  #pragma unroll
  for (int r = 0; r < 4; ++r) {
    const uint4 cv = *(const uint4*)(Cb + (size_t)(row0 + r) * 512 + (l << 3));
    float a0 = exp2_(-bflo(cv.x)), a1 = exp2_(-bfhi(cv.x));
    float a2 = exp2_(-bflo(cv.y)), a3 = exp2_(-bfhi(cv.y));
    float a4 = exp2_(-bflo(cv.z)), a5 = exp2_(-bfhi(cv.z));
    float a6 = exp2_(-bflo(cv.w)), a7 = exp2_(-bfhi(cv.w));
    u32 w0 = (u32)__builtin_amdgcn_cvt_pk_fp8_f32(a0, a1, 0, false);
    w0 = (u32)__builtin_amdgcn_cvt_pk_fp8_f32(a2, a3, (int)w0, true);
    u32 w1 = (u32)__builtin_amdgcn_cvt_pk_fp8_f32(a4, a5, 0, false);
    w1 = (u32)__builtin_amdgcn_cvt_pk_fp8_f32(a6, a7, (int)w1, true);
    Af8[r * 2 + 0] = w0;
    Af8[r * 2 + 1] = w1;
    Tp[r * 4 + 0] = 0x3F803F80u;  // (1.0bf16, 1.0bf16)
    Tp[r * 4 + 1] = 0x3F803F80u;
    Tp[r * 4 + 2] = 0x3F803F80u;
    Tp[r * 4 + 3] = 0x3F803F80u;
  }

  for (int it = 1; it <= 50; ++it) {
    int par = it & 1;
    float dl[4];
    float cp[8] = {0.f,0.f,0.f,0.f,0.f,0.f,0.f,0.f};
    {
      // sigma for my 8 cols
      float sg[8];
      const float4* ps = (const float4*)&sig[l << 3];
      float4 s0 = ps[0], s1 = ps[1];
      sg[0]=s0.x; sg[1]=s0.y; sg[2]=s0.z; sg[3]=s0.w;
      sg[4]=s1.x; sg[5]=s1.y; sg[6]=s1.z; sg[7]=s1.w;
      // ---- fused sweep1+2 per row: Q=A*T (repack), rowsum->delta, colpart += delta*Q ----
      #pragma unroll
      for (int r = 0; r < 4; ++r) {
        f32x2 a01 = __builtin_amdgcn_cvt_pk_f32_fp8((int)Af8[r*2+0], false);
        f32x2 a23 = __builtin_amdgcn_cvt_pk_f32_fp8((int)Af8[r*2+0], true);
        f32x2 a45 = __builtin_amdgcn_cvt_pk_f32_fp8((int)Af8[r*2+1], false);
        f32x2 a67 = __builtin_amdgcn_cvt_pk_f32_fp8((int)Af8[r*2+1], true);
        float q[8];
        float acc = 0.f;
        { u32 tw = Tp[r*4+0]; q[0] = a01.x*bflo(tw); q[1] = a01.y*bfhi(tw);
          Tp[r*4+0] = pkbf(q[0],q[1]); acc = fmaf(q[0],sg[0],acc); acc = fmaf(q[1],sg[1],acc); }
        { u32 tw = Tp[r*4+1]; q[2] = a23.x*bflo(tw); q[3] = a23.y*bfhi(tw);
          Tp[r*4+1] = pkbf(q[2],q[3]); acc = fmaf(q[2],sg[2],acc); acc = fmaf(q[3],sg[3],acc); }
        { u32 tw = Tp[r*4+2]; q[4] = a45.x*bflo(tw); q[5] = a45.y*bfhi(tw);
          Tp[r*4+2] = pkbf(q[4],q[5]); acc = fmaf(q[4],sg[4],acc); acc = fmaf(q[5],sg[5],acc); }
        { u32 tw = Tp[r*4+3]; q[6] = a67.x*bflo(tw); q[7] = a67.y*bfhi(tw);
          Tp[r*4+3] = pkbf(q[6],q[7]); acc = fmaf(q[6],sg[6],acc); acc = fmaf(q[7],sg[7],acc); }
        #pragma unroll
        for (int off = 32; off; off >>= 1) acc += __shfl_xor(acc, off);
        float d = 1.0f / fmaf(yl, acc, ymk[base_n + row0 + r]);
        dl[r] = d;
        #pragma unroll
        for (int c = 0; c < 8; ++c) cp[c] = fmaf(d, q[c], cp[c]);
      }
    }
    // ---- 8-slot colsum tree in LDS (2 rounds, deterministic) ----
    {
      float4 v0, v1;
      v0.x=cp[0]; v0.y=cp[1]; v0.z=cp[2]; v0.w=cp[3];
      v1.x=cp[4]; v1.y=cp[5]; v1.z=cp[6]; v1.w=cp[7];
      float4* dst = (float4*)&cpart[w & 7][l << 3];
      if (w < 8) { dst[0] = v0; dst[1] = v1; }
      __syncthreads();
      if (w >= 8) {
        float4 o0 = dst[0], o1 = dst[1];
        o0.x+=v0.x; o0.y+=v0.y; o0.z+=v0.z; o0.w+=v0.w;
        o1.x+=v1.x; o1.y+=v1.y; o1.z+=v1.z; o1.w+=v1.w;
        dst[0] = o0; dst[1] = o1;
      }
      __syncthreads();
    }
    if (tid < 512) {
      float s = 0.f;
      #pragma unroll
      for (int k = 0; k < 8; ++k) s += cpart[k][tid];
      __hip_atomic_store(&cp_b[(par << 12) + (p << 9) + tid], s, __ATOMIC_RELAXED, __HIP_MEMORY_SCOPE_AGENT);
    }
    batch_barrier(&cnt_b[it - 1], 8);
    if (tid < 512) {
      const float* basep = cp_b + (par << 12);
      float s = 0.f;
      #pragma unroll
      for (int pp = 0; pp < 8; ++pp)
        s += __hip_atomic_load(&basep[(pp << 9) + tid], __ATOMIC_RELAXED, __HIP_MEMORY_SCOPE_AGENT);
      sig[tid] = 1.0f / fmaf(xl, s, xmk[tid]);
    }
    __syncthreads();
    // ---- sweep3: T = Q * delta * sigma' ----
    {
      float sg[8];
      const float4* ps = (const float4*)&sig[l << 3];
      float4 s0 = ps[0], s1 = ps[1];
      sg[0]=s0.x; sg[1]=s0.y; sg[2]=s0.z; sg[3]=s0.w;
      sg[4]=s1.x; sg[5]=s1.y; sg[6]=s1.z; sg[7]=s1.w;
      #pragma unroll
      for (int r = 0; r < 4; ++r) {
        float d = dl[r];
        { u32 tw = Tp[r*4+0]; Tp[r*4+0] = pkbf(bflo(tw)*d*sg[0], bfhi(tw)*d*sg[1]); }
        { u32 tw = Tp[r*4+1]; Tp[r*4+1] = pkbf(bflo(tw)*d*sg[2], bfhi(tw)*d*sg[3]); }
        { u32 tw = Tp[r*4+2]; Tp[r*4+2] = pkbf(bflo(tw)*d*sg[4], bfhi(tw)*d*sg[5]); }
        { u32 tw = Tp[r*4+3]; Tp[r*4+3] = pkbf(bflo(tw)*d*sg[6], bfhi(tw)*d*sg[7]); }
      }
    }
  }

  // ---- final: partial dist = sum Ct2*T (masked: Ct2=3e4 but T=0 exactly) ----
  float accT = 0.f;
  #pragma unroll
  for (int r = 0; r < 4; ++r) {
    const uint4 cv = *(const uint4*)(Cb + (size_t)(row0 + r) * 512 + (l << 3));
    { u32 tw = Tp[r*4+0]; accT = fmaf(bflo(cv.x), bflo(tw), accT); accT = fmaf(bfhi(cv.x), bfhi(tw), accT); }
    { u32 tw = Tp[r*4+1]; accT = fmaf(bflo(cv.y), bflo(tw), accT); accT = fmaf(bfhi(cv.y), bfhi(tw), accT); }
    { u32 tw = Tp[r*4+2]; accT = fmaf(bflo(cv.z), bflo(tw), accT); accT = fmaf(bfhi(cv.z), bfhi(tw), accT); }
    { u32 tw = Tp[r*4+3]; accT = fmaf(bflo(cv.w), bflo(tw), accT); accT = fmaf(bfhi(cv.w), bfhi(tw), accT); }
  }
  #pragma unroll
  for (int off = 32; off; off >>= 1) accT += __shfl_xor(accT, off);
  if (l == 0) redw[w] = accT;
  __syncthreads();
  if (tid == 0) {
    float s = 0.f;
    #pragma unroll
    for (int ww = 0; ww < 16; ++ww) s += redw[ww];
    __hip_atomic_store(&fin_part[(b << 3) + p], s, __ATOMIC_RELAXED, __HIP_MEMORY_SCOPE_AGENT);
  }
  batch_barrier(&cnt_b[50], 8);
  if (p == 0 && tid == 0) {
    float s = 0.f;
    #pragma unroll
    for (int pp = 0; pp < 8; ++pp)
      s += __hip_atomic_load(&fin_part[(b << 3) + pp], __ATOMIC_RELAXED, __HIP_MEMORY_SCOPE_AGENT);
    ot[b] = s * 0.34657359f;  // beta * ln2  (Ct2 is in log2 units)
  }
}

// ---------------- finalize: out = sum_b (ot[b] - llh[b]) ----------------
__global__ __launch_bounds__(64) void k_finalize(const float* __restrict__ llh, const float* __restrict__ ot,
                                                 float* __restrict__ out) {
  int l = threadIdx.x;
  float v = ot[l] - llh[l];
  #pragma unroll
  for (int off = 32; off; off >>= 1) v += __shfl_down(v, off);
  if (l == 0) out[0] = v;
}

extern "C" void kernel_launch(void* const* d_in, const int* in_sizes, int n_in,
                              void* d_out, int out_size, void* d_ws, size_t ws_size,
                              hipStream_t stream) {
  const float* emis  = (const float*)d_in[0];
  const float* txt   = (const float*)d_in[1];
  const float* img   = (const float*)d_in[2];
  const float* startT= (const float*)d_in[3];
  const float* endT  = (const float*)d_in[4];
  const float* trans = (const float*)d_in[5];
  const int*  tags   = (const int*)d_in[6];
  const u8* cmask = (const u8*)d_in[7];
  const u8* xpad  = (const u8*)d_in[8];
  const u8* ypad  = (const u8*)d_in[9];
  char* wsb = (char*)d_ws;
  u16* xh  = (u16*)wsb;                          // 50331648 B (dead after gemm)
  u16* yh  = (u16*)(wsb + 50331648ll);           // 50331648 B (dead after gemm)
  u16* Ct2 = (u16*)(wsb + 100663296ll);          // 33554432 B
  float* ot    = (float*)(wsb + 134217728ll);    // 64 f32
  float* llh   = ot + 64;                        // 64 f32
  int*  flags  = (int*)(llh + 64);
  // ipot scratch aliases the dead xh region (memset AFTER gemm) -- R15-validated layout:
  int*  gcount  = (int*)wsb;                     // 64*64 ints = 16384 B
  float* c_part = (float*)(wsb + 16384ll);       // 64*2*8*512 f32 = 2 MB
  float* fin_part=(float*)(wsb + 16384ll + 2097152ll); // 64*8 f32
  float* out = (float*)d_out;

  hipLaunchKernelGGL(k_detect, dim3(1), dim3(1), 0, stream, (const u32*)cmask, flags);
  hipLaunchKernelGGL(k_normalize, dim3(16384), dim3(256), 0, stream, txt, img, xh, yh);
  hipLaunchKernelGGL(k_gemm_crf, dim3(1088), dim3(256), 0, stream, xh, yh, xpad, ypad, flags, Ct2,
                     emis, tags, cmask, startT, endT, trans, llh);
  hipMemsetAsync(gcount, 0, 64 * 64 * sizeof(int), stream);
  hipLaunchKernelGGL(k_ipot8f8, dim3(512), dim3(1024), 0, stream,
                     Ct2, xpad, ypad, flags, gcount, c_part, fin_part, ot);
  hipLaunchKernelGGL(k_finalize, dim3(1), dim3(64), 0, stream, llh, ot, out);
}

// Round 17
// 888.062 us; speedup vs baseline: 1.4325x; 1.2203x over previous
//
#include <hip/hip_runtime.h>
#include <stdint.h>

typedef unsigned short u16;
typedef unsigned char u8;
typedef unsigned int u32;

#define LOG2E 1.4426950408889634f
#define LN2   0.6931471805599453f

typedef __attribute__((ext_vector_type(2))) float f32x2;

__device__ __forceinline__ float exp2_(float x){ return __builtin_amdgcn_exp2f(x); }
__device__ __forceinline__ float log2_(float x){ return __builtin_amdgcn_logf(x); }
__device__ __forceinline__ float bflo(u32 u){ return __uint_as_float(u << 16); }
__device__ __forceinline__ float bfhi(u32 u){ return __uint_as_float(u & 0xffff0000u); }
__device__ __forceinline__ u16 f2bf(float f){
  u32 u = __float_as_uint(f);
  return (u16)((u + 0x7fffu + ((u >> 16) & 1u)) >> 16);
}
// pack two f32 -> two bf16 in one u32 (1 VALU op on gfx950)
__device__ __forceinline__ u32 pkbf(float lo, float hi){
  u32 r; asm("v_cvt_pk_bf16_f32 %0, %1, %2" : "=v"(r) : "v"(lo), "v"(hi)); return r;
}
// bool input read: stride 1 (u8 bools) or 4 (int32 bools, LE low byte)
__device__ __forceinline__ int rdmask(const u8* p, int i, int st){ return (int)p[(size_t)i * st]; }

// ---------------- detect bool dtype: crf_mask[0,:] is all-true ----------------
__global__ void k_detect(const u32* __restrict__ cmask, int* __restrict__ flags) {
  flags[0] = (cmask[0] == 0x01010101u) ? 1 : 4;
}

// ---------------- normalize rows (txt & img) to bf16 ----------------
__global__ __launch_bounds__(256) void k_normalize(const float* __restrict__ txt,
                                                   const float* __restrict__ img,
                                                   u16* __restrict__ xh, u16* __restrict__ yh) {
  int row = blockIdx.x * 4 + (threadIdx.x >> 6);
  int l = threadIdx.x & 63;
  const float* src; u16* dst;
  if (row < 32768) { src = txt + (size_t)row * 768; dst = xh + (size_t)row * 768; }
  else { int r2 = row - 32768; src = img + (size_t)r2 * 768; dst = yh + (size_t)r2 * 768; }
  float v[12]; float ss = 0.f;
  #pragma unroll
  for (int s = 0; s < 12; ++s) { v[s] = src[l + (s << 6)]; ss = fmaf(v[s], v[s], ss); }
  #pragma unroll
  for (int off = 32; off; off >>= 1) ss += __shfl_xor(ss, off);
  float sc = 1.0f / fmaxf(sqrtf(ss), 1e-5f);
  #pragma unroll
  for (int s = 0; s < 12; ++s) dst[l + (s << 6)] = f2bf(v[s] * sc);
}

// ---------------- cost matrix GEMM + (hidden) CRF (verbatim R13/R14, passing) --------
typedef __attribute__((ext_vector_type(8))) short short8;
typedef __attribute__((ext_vector_type(4))) float f32x4;

__global__ __launch_bounds__(256) void k_gemm_crf(const u16* __restrict__ xh, const u16* __restrict__ yh,
                                                  const u8* __restrict__ xpad, const u8* __restrict__ ypad,
                                                  const int* __restrict__ flags,
                                                  u16* __restrict__ Ct2,
                                                  const float* __restrict__ emis, const int* __restrict__ tags,
                                                  const u8* __restrict__ mask,
                                                  const float* __restrict__ startT, const float* __restrict__ endT,
                                                  const float* __restrict__ trans, float* __restrict__ llh) {
  __shared__ u16 As[128 * 64];
  __shared__ u16 Bs[128 * 64];
  __shared__ float tr[441];
  int st = flags[0];
  int bt = blockIdx.x;
  int tid = threadIdx.x;

  if (bt >= 1024) {
    // ---------------- CRF branch ----------------
    int b = bt - 1024;
    for (int i = tid; i < 441; i += 256) tr[i] = trans[i];
    __syncthreads();
    if (tid >= 64) return;
    int k = tid;
    float accs = 0.f; int cnt = 0;
    for (int t = k; t < 512; t += 64) {
      int mt = rdmask(mask, (t << 6) + b, st);
      cnt += mt;
      int tg = tags[(t << 6) + b];
      if (t == 0) {
        accs += startT[tg] + emis[(size_t)b * 21 + tg];
      } else if (mt) {
        int tgp = tags[((t - 1) << 6) + b];
        accs += tr[tgp * 21 + tg] + emis[((size_t)((t << 6) + b)) * 21 + tg];
      }
    }
    #pragma unroll
    for (int off = 32; off; off >>= 1) { accs += __shfl_down(accs, off); cnt += __shfl_down(cnt, off); }
    float numer = 0.f;
    if (k == 0) {
      int last = tags[((cnt - 1) << 6) + b];
      numer = accs + endT[last];
    }
    int kc = (k < 21) ? k : 20;
    float s = startT[kc] + emis[(size_t)b * 21 + kc];
    for (int t = 1; t < 512; ++t) {
      float z[21];
      float zmax = -3.0e38f;
      #pragma unroll
      for (int j = 0; j < 21; ++j) {
        float sj = __shfl(s, j);
        z[j] = sj + tr[j * 21 + kc];
        zmax = fmaxf(zmax, z[j]);
      }
      float sum = 0.f;
      #pragma unroll
      for (int j = 0; j < 21; ++j) sum += exp2_((z[j] - zmax) * LOG2E);
      float ns = zmax + log2_(sum) * LN2 + emis[((size_t)((t << 6) + b)) * 21 + kc];
      s = rdmask(mask, (t << 6) + b, st) ? ns : s;
    }
    float f = (k < 21) ? (s + endT[kc]) : -3.0e38f;
    float m = f;
    #pragma unroll
    for (int off = 32; off; off >>= 1) m = fmaxf(m, __shfl_xor(m, off));
    float sum = (k < 21) ? exp2_((f - m) * LOG2E) : 0.f;
    #pragma unroll
    for (int off = 32; off; off >>= 1) sum += __shfl_xor(sum, off);
    float denom = m + log2_(sum) * LN2;
    if (k == 0) llh[b] = numer - denom;
    return;
  }

  // ---------------- GEMM branch ----------------
  int b = bt >> 4;
  int tile = bt & 15;
  int tn = tile >> 2, tm = tile & 3;
  const u16* Ab = yh + ((size_t)b * 512 + tn * 128) * 768;
  const u16* Bb = xh + ((size_t)b * 512 + tm * 128) * 768;
  int w = tid >> 6, l = tid & 63;
  int wr = (w >> 1) << 6, wc = (w & 1) << 6;
  f32x4 acc[4][4] = {};
  for (int k0 = 0; k0 < 768; k0 += 64) {
    #pragma unroll
    for (int q = 0; q < 4; ++q) {
      int slot = (q << 8) + tid;
      int row = slot >> 3, col = (slot & 7) << 3;
      uint4 va = *(const uint4*)(Ab + row * 768 + k0 + col);
      uint4 vb = *(const uint4*)(Bb + row * 768 + k0 + col);
      *(uint4*)((char*)As + slot * 16) = va;
      *(uint4*)((char*)Bs + slot * 16) = vb;
    }
    __syncthreads();
    #pragma unroll
    for (int kk = 0; kk < 64; kk += 32) {
      int cb = (kk + ((l >> 4) << 3)) * 2;
      short8 a[4], bb[4];
      #pragma unroll
      for (int i = 0; i < 4; ++i)
        a[i] = *(const short8*)((const char*)As + (wr + (i << 4) + (l & 15)) * 128 + cb);
      #pragma unroll
      for (int j = 0; j < 4; ++j)
        bb[j] = *(const short8*)((const char*)Bs + (wc + (j << 4) + (l & 15)) * 128 + cb);
      #pragma unroll
      for (int i = 0; i < 4; ++i)
        #pragma unroll
        for (int j = 0; j < 4; ++j)
          acc[i][j] = __builtin_amdgcn_mfma_f32_16x16x32_bf16(a[i], bb[j], acc[i][j], 0, 0, 0);
    }
    __syncthreads();
  }
  int n0 = (tn << 7) + wr, m0 = (tm << 7) + wc;
  #pragma unroll
  for (int i = 0; i < 4; ++i) {
    #pragma unroll
    for (int j = 0; j < 4; ++j) {
      int m = m0 + (j << 4) + (l & 15);
      int xpm = rdmask(xpad, b * 512 + m, st);
      #pragma unroll
      for (int r = 0; r < 4; ++r) {
        int n = n0 + (i << 4) + ((l >> 4) << 2) + r;
        float v = 2.8853901f * (1.0f - acc[i][j][r]);
        if (xpm | rdmask(ypad, b * 512 + n, st)) v = 30000.0f;
        Ct2[((size_t)(b * 512 + n) << 9) + m] = f2bf(v);
      }
    }
  }
}

// ---------------- cross-block per-batch barrier (agent-scope) ----------------
__device__ __forceinline__ void batch_barrier(int* cnt, int target) {
  __syncthreads();
  if (threadIdx.x == 0) {
    __hip_atomic_fetch_add(cnt, 1, __ATOMIC_RELEASE, __HIP_MEMORY_SCOPE_AGENT);
    while (__hip_atomic_load(cnt, __ATOMIC_ACQUIRE, __HIP_MEMORY_SCOPE_AGENT) < target)
      __builtin_amdgcn_s_sleep(1);
  }
  __syncthreads();
}

// ---------------- IPOT: lazy-sweep3 variant of R14 (passing base) -----------
// Structure = R14: 4 blocks/batch (b=bid&63 XCD co-located), 1024 thr, A fp8 in
// LDS, state packed bf16 in Tp[32]. NEW: state u stores Q (not T); per-row delta
// persists in dl[8] across iterations; sweep1 computes q_new = a*(u*dl_old[r])*sg[c]
// -- the sigma' read at iter start IS the one T_{k-1} needs, so sweep3 vanishes.
// Init u=xl, dl=1 reproduces Q_1 = A exactly (masked: a=0 -> q=0). Epilogue
// contracts Ct2 with T_50 = u*dl[r]*sg[c]. ~20% fewer VALU ops/elem than R14.
__global__ __launch_bounds__(1024)
void k_ipot_lz(const u16* __restrict__ Ct2,
               const u8* __restrict__ xpad, const u8* __restrict__ ypad,
               const int* __restrict__ flags,
               int* __restrict__ gcount, float* __restrict__ c_part,
               float* __restrict__ fin_part,
               float* __restrict__ ot) {
  __shared__ __align__(16) u32  A_l[128 * 128];      // 65536 B (fp8, 512 cols/row)
  __shared__ __align__(16) float cpart[4][512];      //  8192 B
  __shared__ __align__(16) float sig[512];           //   2048 B
  __shared__ __align__(16) float xmk[512];           //   2048 B
  __shared__ __align__(16) float ymk[512];           //   2048 B
  __shared__ float redw[16];
  __shared__ int cnti[2];

  int bid = blockIdx.x;
  int b = bid & 63, p = bid >> 6;
  int tid = threadIdx.x;
  int w = tid >> 6, l = tid & 63;
  int st = flags[0];

  if (tid < 2) cnti[tid] = 0;
  __syncthreads();
  if (tid < 512) {
    int xp = rdmask(xpad, (b << 9) + tid, st) ? 1 : 0;
    int yp = rdmask(ypad, (b << 9) + tid, st) ? 1 : 0;
    xmk[tid] = xp ? 1e4f : 0.f;
    ymk[tid] = yp ? 1e4f : 0.f;
    atomicAdd(&cnti[0], 1 - xp);
    atomicAdd(&cnti[1], 1 - yp);
  }
  __syncthreads();
  float xl = (float)cnti[0], yl = (float)cnti[1];
  if (tid < 512) sig[tid] = (xmk[tid] > 0.f) ? 0.f : (1.0f / xl);

  const int base_n = p << 7;
  const int row0 = (w << 3);                    // local row of this wave
  const u16* Cb = Ct2 + ((size_t)(b * 512 + base_n) << 9);
  int* cnt_b = gcount + (b << 6);
  float* cp_b = c_part + ((size_t)b << 12);     // 2 parities * 4 parts * 512

  // ---- precompute A = exp2(-Ct2) into LDS (fp8); init u = xl (packed), dl = 1 ----
  u32 Tp[32];
  float dl[8];
  u32 xlpk = pkbf(xl, xl);
  #pragma unroll
  for (int r = 0; r < 8; ++r) {
    const uint4 cv = *(const uint4*)(Cb + (size_t)(row0 + r) * 512 + (l << 3));
    float a0 = exp2_(-bflo(cv.x)), a1 = exp2_(-bfhi(cv.x));
    float a2 = exp2_(-bflo(cv.y)), a3 = exp2_(-bfhi(cv.y));
    float a4 = exp2_(-bflo(cv.z)), a5 = exp2_(-bfhi(cv.z));
    float a6 = exp2_(-bflo(cv.w)), a7 = exp2_(-bfhi(cv.w));
    u32 w0 = (u32)__builtin_amdgcn_cvt_pk_fp8_f32(a0, a1, 0, false);
    w0 = (u32)__builtin_amdgcn_cvt_pk_fp8_f32(a2, a3, (int)w0, true);
    u32 w1 = (u32)__builtin_amdgcn_cvt_pk_fp8_f32(a4, a5, 0, false);
    w1 = (u32)__builtin_amdgcn_cvt_pk_fp8_f32(a6, a7, (int)w1, true);
    uint2 wv; wv.x = w0; wv.y = w1;
    *(uint2*)(A_l + (row0 + r) * 128 + (l << 1)) = wv;
    Tp[r * 4 + 0] = xlpk;
    Tp[r * 4 + 1] = xlpk;
    Tp[r * 4 + 2] = xlpk;
    Tp[r * 4 + 3] = xlpk;
    dl[r] = 1.0f;
  }
  __syncthreads();

  for (int it = 1; it <= 50; ++it) {
    int par = it & 1;
    {
      // sigma' entering this iter (= the factor T_{it-1} owes): my 8 cols
      float sg[8];
      const float4* ps = (const float4*)&sig[l << 3];
      float4 s0 = ps[0], s1 = ps[1];
      sg[0]=s0.x; sg[1]=s0.y; sg[2]=s0.z; sg[3]=s0.w;
      sg[4]=s1.x; sg[5]=s1.y; sg[6]=s1.z; sg[7]=s1.w;
      // ---- sweep1 (lazy T): q = a * (u*dl_old[r]) * sg[c]; rowsum -> new delta ----
      #pragma unroll
      for (int r = 0; r < 8; ++r) {
        const uint2 av = *(const uint2*)(A_l + (row0 + r) * 128 + (l << 1));
        f32x2 a01 = __builtin_amdgcn_cvt_pk_f32_fp8((int)av.x, false);
        f32x2 a23 = __builtin_amdgcn_cvt_pk_f32_fp8((int)av.x, true);
        f32x2 a45 = __builtin_amdgcn_cvt_pk_f32_fp8((int)av.y, false);
        f32x2 a67 = __builtin_amdgcn_cvt_pk_f32_fp8((int)av.y, true);
        float dold = dl[r];
        float acc = 0.f;
        { u32 tw = Tp[r*4+0];
          float q0 = bflo(tw)*dold*a01.x*sg[0], q1 = bfhi(tw)*dold*a01.y*sg[1];
          Tp[r*4+0] = pkbf(q0,q1); acc = fmaf(q0,sg[0],acc); acc = fmaf(q1,sg[1],acc); }
        { u32 tw = Tp[r*4+1];
          float q0 = bflo(tw)*dold*a23.x*sg[2], q1 = bfhi(tw)*dold*a23.y*sg[3];
          Tp[r*4+1] = pkbf(q0,q1); acc = fmaf(q0,sg[2],acc); acc = fmaf(q1,sg[3],acc); }
        { u32 tw = Tp[r*4+2];
          float q0 = bflo(tw)*dold*a45.x*sg[4], q1 = bfhi(tw)*dold*a45.y*sg[5];
          Tp[r*4+2] = pkbf(q0,q1); acc = fmaf(q0,sg[4],acc); acc = fmaf(q1,sg[5],acc); }
        { u32 tw = Tp[r*4+3];
          float q0 = bflo(tw)*dold*a67.x*sg[6], q1 = bfhi(tw)*dold*a67.y*sg[7];
          Tp[r*4+3] = pkbf(q0,q1); acc = fmaf(q0,sg[6],acc); acc = fmaf(q1,sg[7],acc); }
        #pragma unroll
        for (int off = 32; off; off >>= 1) acc += __shfl_xor(acc, off);
        dl[r] = 1.0f / fmaf(yl, acc, ymk[base_n + row0 + r]);
      }
    }
    // ---- sweep2: colpart = sum_r delta_new[r] * q ----
    {
      float cp[8] = {0.f,0.f,0.f,0.f,0.f,0.f,0.f,0.f};
      #pragma unroll
      for (int r = 0; r < 8; ++r) {
        float d = dl[r];
        { u32 tw = Tp[r*4+0]; cp[0] = fmaf(bflo(tw),d,cp[0]); cp[1] = fmaf(bfhi(tw),d,cp[1]); }
        { u32 tw = Tp[r*4+1]; cp[2] = fmaf(bflo(tw),d,cp[2]); cp[3] = fmaf(bfhi(tw),d,cp[3]); }
        { u32 tw = Tp[r*4+2]; cp[4] = fmaf(bflo(tw),d,cp[4]); cp[5] = fmaf(bfhi(tw),d,cp[5]); }
        { u32 tw = Tp[r*4+3]; cp[6] = fmaf(bflo(tw),d,cp[6]); cp[7] = fmaf(bfhi(tw),d,cp[7]); }
      }
      // ---- 4-slot colsum tree in LDS (deterministic, 4 rounds; R14 verbatim) ----
      float4 v0, v1;
      v0.x=cp[0]; v0.y=cp[1]; v0.z=cp[2]; v0.w=cp[3];
      v1.x=cp[4]; v1.y=cp[5]; v1.z=cp[6]; v1.w=cp[7];
      float4* dst = (float4*)&cpart[w & 3][l << 3];
      if (w < 4) { dst[0] = v0; dst[1] = v1; }
      __syncthreads();
      if (w >= 4 && w < 8) {
        float4 o0 = dst[0], o1 = dst[1];
        o0.x+=v0.x; o0.y+=v0.y; o0.z+=v0.z; o0.w+=v0.w;
        o1.x+=v1.x; o1.y+=v1.y; o1.z+=v1.z; o1.w+=v1.w;
        dst[0] = o0; dst[1] = o1;
      }
      __syncthreads();
      if (w >= 8 && w < 12) {
        float4 o0 = dst[0], o1 = dst[1];
        o0.x+=v0.x; o0.y+=v0.y; o0.z+=v0.z; o0.w+=v0.w;
        o1.x+=v1.x; o1.y+=v1.y; o1.z+=v1.z; o1.w+=v1.w;
        dst[0] = o0; dst[1] = o1;
      }
      __syncthreads();
      if (w >= 12) {
        float4 o0 = dst[0], o1 = dst[1];
        o0.x+=v0.x; o0.y+=v0.y; o0.z+=v0.z; o0.w+=v0.w;
        o1.x+=v1.x; o1.y+=v1.y; o1.z+=v1.z; o1.w+=v1.w;
        dst[0] = o0; dst[1] = o1;
      }
      __syncthreads();
    }
    if (tid < 512) {
      float s = cpart[0][tid] + cpart[1][tid] + cpart[2][tid] + cpart[3][tid];
      __hip_atomic_store(&cp_b[(par << 11) + (p << 9) + tid], s, __ATOMIC_RELAXED, __HIP_MEMORY_SCOPE_AGENT);
    }
    batch_barrier(&cnt_b[it - 1], 4);
    if (tid < 512) {
      const float* basep = cp_b + (par << 11);
      float s = __hip_atomic_load(&basep[tid], __ATOMIC_RELAXED, __HIP_MEMORY_SCOPE_AGENT);
      s += __hip_atomic_load(&basep[512 + tid], __ATOMIC_RELAXED, __HIP_MEMORY_SCOPE_AGENT);
      s += __hip_atomic_load(&basep[1024 + tid], __ATOMIC_RELAXED, __HIP_MEMORY_SCOPE_AGENT);
      s += __hip_atomic_load(&basep[1536 + tid], __ATOMIC_RELAXED, __HIP_MEMORY_SCOPE_AGENT);
      sig[tid] = 1.0f / fmaf(xl, s, xmk[tid]);
    }
    __syncthreads();
    // ---- no sweep3: delta stays in dl[], sigma' stays in sig[] for next iter ----
  }

  // ---- final: T_50 = u * dl[r] * sg[c]; partial dist = sum Ct2*T ----
  float sgf[8];
  {
    const float4* ps = (const float4*)&sig[l << 3];
    float4 s0 = ps[0], s1 = ps[1];
    sgf[0]=s0.x; sgf[1]=s0.y; sgf[2]=s0.z; sgf[3]=s0.w;
    sgf[4]=s1.x; sgf[5]=s1.y; sgf[6]=s1.z; sgf[7]=s1.w;
  }
  float accT = 0.f;
  #pragma unroll
  for (int r = 0; r < 8; ++r) {
    const uint4 cv = *(const uint4*)(Cb + (size_t)(row0 + r) * 512 + (l << 3));
    float d = dl[r];
    { u32 tw = Tp[r*4+0];
      accT = fmaf(bflo(cv.x), bflo(tw)*d*sgf[0], accT); accT = fmaf(bfhi(cv.x), bfhi(tw)*d*sgf[1], accT); }
    { u32 tw = Tp[r*4+1];
      accT = fmaf(bflo(cv.y), bflo(tw)*d*sgf[2], accT); accT = fmaf(bfhi(cv.y), bfhi(tw)*d*sgf[3], accT); }
    { u32 tw = Tp[r*4+2];
      accT = fmaf(bflo(cv.z), bflo(tw)*d*sgf[4], accT); accT = fmaf(bfhi(cv.z), bfhi(tw)*d*sgf[5], accT); }
    { u32 tw = Tp[r*4+3];
      accT = fmaf(bflo(cv.w), bflo(tw)*d*sgf[6], accT); accT = fmaf(bfhi(cv.w), bfhi(tw)*d*sgf[7], accT); }
  }
  #pragma unroll
  for (int off = 32; off; off >>= 1) accT += __shfl_xor(accT, off);
  if (l == 0) redw[w] = accT;
  __syncthreads();
  if (tid == 0) {
    float s = 0.f;
    #pragma unroll
    for (int ww = 0; ww < 16; ++ww) s += redw[ww];
    __hip_atomic_store(&fin_part[(b << 2) + p], s, __ATOMIC_RELAXED, __HIP_MEMORY_SCOPE_AGENT);
  }
  batch_barrier(&cnt_b[50], 4);
  if (p == 0 && tid == 0) {
    float s = 0.f;
    #pragma unroll
    for (int pp = 0; pp < 4; ++pp)
      s += __hip_atomic_load(&fin_part[(b << 2) + pp], __ATOMIC_RELAXED, __HIP_MEMORY_SCOPE_AGENT);
    ot[b] = s * 0.34657359f;  // beta * ln2  (Ct2 is in log2 units)
  }
}

// ---------------- finalize: out = sum_b (ot[b] - llh[b]) ----------------
__global__ __launch_bounds__(64) void k_finalize(const float* __restrict__ llh, const float* __restrict__ ot,
                                                 float* __restrict__ out) {
  int l = threadIdx.x;
  float v = ot[l] - llh[l];
  #pragma unroll
  for (int off = 32; off; off >>= 1) v += __shfl_down(v, off);
  if (l == 0) out[0] = v;
}

extern "C" void kernel_launch(void* const* d_in, const int* in_sizes, int n_in,
                              void* d_out, int out_size, void* d_ws, size_t ws_size,
                              hipStream_t stream) {
  const float* emis  = (const float*)d_in[0];
  const float* txt   = (const float*)d_in[1];
  const float* img   = (const float*)d_in[2];
  const float* startT= (const float*)d_in[3];
  const float* endT  = (const float*)d_in[4];
  const float* trans = (const float*)d_in[5];
  const int*  tags   = (const int*)d_in[6];
  const u8* cmask = (const u8*)d_in[7];
  const u8* xpad  = (const u8*)d_in[8];
  const u8* ypad  = (const u8*)d_in[9];
  char* wsb = (char*)d_ws;
  u16* xh  = (u16*)wsb;                          // 50331648 B
  u16* yh  = (u16*)(wsb + 50331648ll);           // 50331648 B
  u16* Ct2 = (u16*)(wsb + 100663296ll);          // 33554432 B
  float* ot    = (float*)(wsb + 134217728ll);    // 64
  float* llh   = ot + 64;                        // 64
  int*  flags  = (int*)(llh + 64);
  int*  gcount = (int*)(wsb + 134218752ll);      // 64*64 ints = 16384 B
  float* c_part= (float*)(wsb + 134235136ll);    // 64*2*4*512 f32 = 1 MB
  float* fin_part=(float*)(wsb + 135283712ll);   // 64*4 f32
  float* out = (float*)d_out;

  hipMemsetAsync(gcount, 0, 64 * 64 * sizeof(int), stream);
  hipLaunchKernelGGL(k_detect, dim3(1), dim3(1), 0, stream, (const u32*)cmask, flags);
  hipLaunchKernelGGL(k_normalize, dim3(16384), dim3(256), 0, stream, txt, img, xh, yh);
  hipLaunchKernelGGL(k_gemm_crf, dim3(1088), dim3(256), 0, stream, xh, yh, xpad, ypad, flags, Ct2,
                     emis, tags, cmask, startT, endT, trans, llh);
  hipLaunchKernelGGL(k_ipot_lz, dim3(256), dim3(1024), 0, stream,
                     Ct2, xpad, ypad, flags, gcount, c_part, fin_part, ot);
  hipLaunchKernelGGL(k_finalize, dim3(1), dim3(64), 0, stream, llh, ot, out);
}

// Round 18
// 741.758 us; speedup vs baseline: 1.7150x; 1.1972x over previous
//
#include <hip/hip_runtime.h>
#include <stdint.h>

typedef unsigned short u16;
typedef unsigned char u8;
typedef unsigned int u32;

#define LOG2E 1.4426950408889634f
#define LN2   0.6931471805599453f

typedef __attribute__((ext_vector_type(2))) float f32x2;

__device__ __forceinline__ float exp2_(float x){ return __builtin_amdgcn_exp2f(x); }
__device__ __forceinline__ float log2_(float x){ return __builtin_amdgcn_logf(x); }
__device__ __forceinline__ float bflo(u32 u){ return __uint_as_float(u << 16); }
__device__ __forceinline__ float bfhi(u32 u){ return __uint_as_float(u & 0xffff0000u); }
__device__ __forceinline__ u16 f2bf(float f){
  u32 u = __float_as_uint(f);
  return (u16)((u + 0x7fffu + ((u >> 16) & 1u)) >> 16);
}
// pack two f32 -> two bf16 in one u32 (1 VALU op on gfx950)
__device__ __forceinline__ u32 pkbf(float lo, float hi){
  u32 r; asm("v_cvt_pk_bf16_f32 %0, %1, %2" : "=v"(r) : "v"(lo), "v"(hi)); return r;
}
// bool input read: stride 1 (u8 bools) or 4 (int32 bools, LE low byte)
__device__ __forceinline__ int rdmask(const u8* p, int i, int st){ return (int)p[(size_t)i * st]; }

// ---------------- detect bool dtype: crf_mask[0,:] is all-true ----------------
__global__ void k_detect(const u32* __restrict__ cmask, int* __restrict__ flags) {
  flags[0] = (cmask[0] == 0x01010101u) ? 1 : 4;
}

// ---------------- normalize rows (txt & img) to bf16 ----------------
__global__ __launch_bounds__(256) void k_normalize(const float* __restrict__ txt,
                                                   const float* __restrict__ img,
                                                   u16* __restrict__ xh, u16* __restrict__ yh) {
  int row = blockIdx.x * 4 + (threadIdx.x >> 6);
  int l = threadIdx.x & 63;
  const float* src; u16* dst;
  if (row < 32768) { src = txt + (size_t)row * 768; dst = xh + (size_t)row * 768; }
  else { int r2 = row - 32768; src = img + (size_t)r2 * 768; dst = yh + (size_t)r2 * 768; }
  float v[12]; float ss = 0.f;
  #pragma unroll
  for (int s = 0; s < 12; ++s) { v[s] = src[l + (s << 6)]; ss = fmaf(v[s], v[s], ss); }
  #pragma unroll
  for (int off = 32; off; off >>= 1) ss += __shfl_xor(ss, off);
  float sc = 1.0f / fmaxf(sqrtf(ss), 1e-5f);
  #pragma unroll
  for (int s = 0; s < 12; ++s) dst[l + (s << 6)] = f2bf(v[s] * sc);
}

// ---------------- cost matrix GEMM + (hidden) CRF (verbatim R13/R14, passing) --------
typedef __attribute__((ext_vector_type(8))) short short8;
typedef __attribute__((ext_vector_type(4))) float f32x4;

__global__ __launch_bounds__(256) void k_gemm_crf(const u16* __restrict__ xh, const u16* __restrict__ yh,
                                                  const u8* __restrict__ xpad, const u8* __restrict__ ypad,
                                                  const int* __restrict__ flags,
                                                  u16* __restrict__ Ct2,
                                                  const float* __restrict__ emis, const int* __restrict__ tags,
                                                  const u8* __restrict__ mask,
                                                  const float* __restrict__ startT, const float* __restrict__ endT,
                                                  const float* __restrict__ trans, float* __restrict__ llh) {
  __shared__ u16 As[128 * 64];
  __shared__ u16 Bs[128 * 64];
  __shared__ float tr[441];
  int st = flags[0];
  int bt = blockIdx.x;
  int tid = threadIdx.x;

  if (bt >= 1024) {
    // ---------------- CRF branch ----------------
    int b = bt - 1024;
    for (int i = tid; i < 441; i += 256) tr[i] = trans[i];
    __syncthreads();
    if (tid >= 64) return;
    int k = tid;
    float accs = 0.f; int cnt = 0;
    for (int t = k; t < 512; t += 64) {
      int mt = rdmask(mask, (t << 6) + b, st);
      cnt += mt;
      int tg = tags[(t << 6) + b];
      if (t == 0) {
        accs += startT[tg] + emis[(size_t)b * 21 + tg];
      } else if (mt) {
        int tgp = tags[((t - 1) << 6) + b];
        accs += tr[tgp * 21 + tg] + emis[((size_t)((t << 6) + b)) * 21 + tg];
      }
    }
    #pragma unroll
    for (int off = 32; off; off >>= 1) { accs += __shfl_down(accs, off); cnt += __shfl_down(cnt, off); }
    float numer = 0.f;
    if (k == 0) {
      int last = tags[((cnt - 1) << 6) + b];
      numer = accs + endT[last];
    }
    int kc = (k < 21) ? k : 20;
    float s = startT[kc] + emis[(size_t)b * 21 + kc];
    for (int t = 1; t < 512; ++t) {
      float z[21];
      float zmax = -3.0e38f;
      #pragma unroll
      for (int j = 0; j < 21; ++j) {
        float sj = __shfl(s, j);
        z[j] = sj + tr[j * 21 + kc];
        zmax = fmaxf(zmax, z[j]);
      }
      float sum = 0.f;
      #pragma unroll
      for (int j = 0; j < 21; ++j) sum += exp2_((z[j] - zmax) * LOG2E);
      float ns = zmax + log2_(sum) * LN2 + emis[((size_t)((t << 6) + b)) * 21 + kc];
      s = rdmask(mask, (t << 6) + b, st) ? ns : s;
    }
    float f = (k < 21) ? (s + endT[kc]) : -3.0e38f;
    float m = f;
    #pragma unroll
    for (int off = 32; off; off >>= 1) m = fmaxf(m, __shfl_xor(m, off));
    float sum = (k < 21) ? exp2_((f - m) * LOG2E) : 0.f;
    #pragma unroll
    for (int off = 32; off; off >>= 1) sum += __shfl_xor(sum, off);
    float denom = m + log2_(sum) * LN2;
    if (k == 0) llh[b] = numer - denom;
    return;
  }

  // ---------------- GEMM branch ----------------
  int b = bt >> 4;
  int tile = bt & 15;
  int tn = tile >> 2, tm = tile & 3;
  const u16* Ab = yh + ((size_t)b * 512 + tn * 128) * 768;
  const u16* Bb = xh + ((size_t)b * 512 + tm * 128) * 768;
  int w = tid >> 6, l = tid & 63;
  int wr = (w >> 1) << 6, wc = (w & 1) << 6;
  f32x4 acc[4][4] = {};
  for (int k0 = 0; k0 < 768; k0 += 64) {
    #pragma unroll
    for (int q = 0; q < 4; ++q) {
      int slot = (q << 8) + tid;
      int row = slot >> 3, col = (slot & 7) << 3;
      uint4 va = *(const uint4*)(Ab + row * 768 + k0 + col);
      uint4 vb = *(const uint4*)(Bb + row * 768 + k0 + col);
      *(uint4*)((char*)As + slot * 16) = va;
      *(uint4*)((char*)Bs + slot * 16) = vb;
    }
    __syncthreads();
    #pragma unroll
    for (int kk = 0; kk < 64; kk += 32) {
      int cb = (kk + ((l >> 4) << 3)) * 2;
      short8 a[4], bb[4];
      #pragma unroll
      for (int i = 0; i < 4; ++i)
        a[i] = *(const short8*)((const char*)As + (wr + (i << 4) + (l & 15)) * 128 + cb);
      #pragma unroll
      for (int j = 0; j < 4; ++j)
        bb[j] = *(const short8*)((const char*)Bs + (wc + (j << 4) + (l & 15)) * 128 + cb);
      #pragma unroll
      for (int i = 0; i < 4; ++i)
        #pragma unroll
        for (int j = 0; j < 4; ++j)
          acc[i][j] = __builtin_amdgcn_mfma_f32_16x16x32_bf16(a[i], bb[j], acc[i][j], 0, 0, 0);
    }
    __syncthreads();
  }
  int n0 = (tn << 7) + wr, m0 = (tm << 7) + wc;
  #pragma unroll
  for (int i = 0; i < 4; ++i) {
    #pragma unroll
    for (int j = 0; j < 4; ++j) {
      int m = m0 + (j << 4) + (l & 15);
      int xpm = rdmask(xpad, b * 512 + m, st);
      #pragma unroll
      for (int r = 0; r < 4; ++r) {
        int n = n0 + (i << 4) + ((l >> 4) << 2) + r;
        float v = 2.8853901f * (1.0f - acc[i][j][r]);
        if (xpm | rdmask(ypad, b * 512 + n, st)) v = 30000.0f;
        Ct2[((size_t)(b * 512 + n) << 9) + m] = f2bf(v);
      }
    }
  }
}

// ---------------- cross-block per-batch barrier (agent-scope) ----------------
__device__ __forceinline__ void batch_barrier(int* cnt, int target) {
  __syncthreads();
  if (threadIdx.x == 0) {
    __hip_atomic_fetch_add(cnt, 1, __ATOMIC_RELEASE, __HIP_MEMORY_SCOPE_AGENT);
    while (__hip_atomic_load(cnt, __ATOMIC_ACQUIRE, __HIP_MEMORY_SCOPE_AGENT) < target)
      __builtin_amdgcn_s_sleep(1);
  }
  __syncthreads();
}

// ---------------- IPOT: R14 base + butterfly multi-reduce + 1-sync colsum ----
// Structure = R14 (passing): 4 blocks/batch (b=bid&63 XCD co-located), 1024 thr,
// A fp8-e4m3 in LDS, T packed bf16 (Tp[32]), eager sweep3. Block-local changes:
//  * Row reduce: 8-value butterfly fold (shfl_xor 1,2,4 give/keep halves, then
//    8,16,32, then 8 broadcasts) = 18 shuffles/thread/iter vs 48.
//    Lane l ends holding row r = 4(l&1)+2((l>>1)&1)+((l>>2)&1) of its wave.
//  * Colsum: cpart[16][512] write-once + 1 __syncthreads (vs 4-round RMW tree).
// dl[8] still dies before batch_barrier (R17's spill was dl persisting across it).
__global__ __launch_bounds__(1024)
void k_ipot_f8b(const u16* __restrict__ Ct2,
                const u8* __restrict__ xpad, const u8* __restrict__ ypad,
                const int* __restrict__ flags,
                int* __restrict__ gcount, float* __restrict__ c_part,
                float* __restrict__ fin_part,
                float* __restrict__ ot) {
  __shared__ __align__(16) u32  A_l[128 * 128];      // 65536 B (fp8, 512 cols/row)
  __shared__ __align__(16) float cpart[16][512];     // 32768 B
  __shared__ __align__(16) float sig[512];           //  2048 B
  __shared__ __align__(16) float xmk[512];           //  2048 B
  __shared__ __align__(16) float ymk[512];           //  2048 B
  __shared__ float redw[16];
  __shared__ int cnti[2];

  int bid = blockIdx.x;
  int b = bid & 63, p = bid >> 6;
  int tid = threadIdx.x;
  int w = tid >> 6, l = tid & 63;
  int st = flags[0];

  if (tid < 2) cnti[tid] = 0;
  __syncthreads();
  if (tid < 512) {
    int xp = rdmask(xpad, (b << 9) + tid, st) ? 1 : 0;
    int yp = rdmask(ypad, (b << 9) + tid, st) ? 1 : 0;
    xmk[tid] = xp ? 1e4f : 0.f;
    ymk[tid] = yp ? 1e4f : 0.f;
    atomicAdd(&cnti[0], 1 - xp);
    atomicAdd(&cnti[1], 1 - yp);
  }
  __syncthreads();
  float xl = (float)cnti[0], yl = (float)cnti[1];
  if (tid < 512) sig[tid] = (xmk[tid] > 0.f) ? 0.f : (1.0f / xl);

  const int base_n = p << 7;
  const int row0 = (w << 3);                    // local row of this wave
  const u16* Cb = Ct2 + ((size_t)(b * 512 + base_n) << 9);
  int* cnt_b = gcount + (b << 6);
  float* cp_b = c_part + ((size_t)b << 12);     // 2 parities * 4 parts * 512

  // ---- precompute A = exp2(-Ct2) into LDS (fp8), init T = 1 (packed bf16) ----
  u32 Tp[32];
  #pragma unroll
  for (int r = 0; r < 8; ++r) {
    const uint4 cv = *(const uint4*)(Cb + (size_t)(row0 + r) * 512 + (l << 3));
    float a0 = exp2_(-bflo(cv.x)), a1 = exp2_(-bfhi(cv.x));
    float a2 = exp2_(-bflo(cv.y)), a3 = exp2_(-bfhi(cv.y));
    float a4 = exp2_(-bflo(cv.z)), a5 = exp2_(-bfhi(cv.z));
    float a6 = exp2_(-bflo(cv.w)), a7 = exp2_(-bfhi(cv.w));
    u32 w0 = (u32)__builtin_amdgcn_cvt_pk_fp8_f32(a0, a1, 0, false);
    w0 = (u32)__builtin_amdgcn_cvt_pk_fp8_f32(a2, a3, (int)w0, true);
    u32 w1 = (u32)__builtin_amdgcn_cvt_pk_fp8_f32(a4, a5, 0, false);
    w1 = (u32)__builtin_amdgcn_cvt_pk_fp8_f32(a6, a7, (int)w1, true);
    uint2 wv; wv.x = w0; wv.y = w1;
    *(uint2*)(A_l + (row0 + r) * 128 + (l << 1)) = wv;
    Tp[r * 4 + 0] = 0x3F803F80u;  // (1.0bf16, 1.0bf16)
    Tp[r * 4 + 1] = 0x3F803F80u;
    Tp[r * 4 + 2] = 0x3F803F80u;
    Tp[r * 4 + 3] = 0x3F803F80u;
  }
  __syncthreads();

  const int k0b = l & 1, k1b = (l >> 1) & 1, k2b = (l >> 2) & 1;
  const int myr = (k0b << 2) | (k1b << 1) | k2b;
  const float ymk_mine_base = 0.f; (void)ymk_mine_base;

  for (int it = 1; it <= 50; ++it) {
    int par = it & 1;
    float dl[8];
    {
      // sigma for my 8 cols
      float sg[8];
      const float4* ps = (const float4*)&sig[l << 3];
      float4 s0v = ps[0], s1v = ps[1];
      sg[0]=s0v.x; sg[1]=s0v.y; sg[2]=s0v.z; sg[3]=s0v.w;
      sg[4]=s1v.x; sg[5]=s1v.y; sg[6]=s1v.z; sg[7]=s1v.w;
      // ---- sweep1: Q = A*T (repack into Tp), rowpart rp[r] = sum_c Q*sg ----
      float rp[8];
      #pragma unroll
      for (int r = 0; r < 8; ++r) {
        const uint2 av = *(const uint2*)(A_l + (row0 + r) * 128 + (l << 1));
        f32x2 a01 = __builtin_amdgcn_cvt_pk_f32_fp8((int)av.x, false);
        f32x2 a23 = __builtin_amdgcn_cvt_pk_f32_fp8((int)av.x, true);
        f32x2 a45 = __builtin_amdgcn_cvt_pk_f32_fp8((int)av.y, false);
        f32x2 a67 = __builtin_amdgcn_cvt_pk_f32_fp8((int)av.y, true);
        float acc = 0.f;
        { u32 tw = Tp[r*4+0]; float q0 = a01.x*bflo(tw), q1 = a01.y*bfhi(tw);
          Tp[r*4+0] = pkbf(q0,q1); acc = fmaf(q0,sg[0],acc); acc = fmaf(q1,sg[1],acc); }
        { u32 tw = Tp[r*4+1]; float q0 = a23.x*bflo(tw), q1 = a23.y*bfhi(tw);
          Tp[r*4+1] = pkbf(q0,q1); acc = fmaf(q0,sg[2],acc); acc = fmaf(q1,sg[3],acc); }
        { u32 tw = Tp[r*4+2]; float q0 = a45.x*bflo(tw), q1 = a45.y*bfhi(tw);
          Tp[r*4+2] = pkbf(q0,q1); acc = fmaf(q0,sg[4],acc); acc = fmaf(q1,sg[5],acc); }
        { u32 tw = Tp[r*4+3]; float q0 = a67.x*bflo(tw), q1 = a67.y*bfhi(tw);
          Tp[r*4+3] = pkbf(q0,q1); acc = fmaf(q0,sg[6],acc); acc = fmaf(q1,sg[7],acc); }
        rp[r] = acc;
      }
      // ---- butterfly multi-reduce: 8 rowsums over 64 lanes in 10+8 shuffles ----
      float s0 = (k0b ? rp[4] : rp[0]) + __shfl_xor(k0b ? rp[0] : rp[4], 1);
      float s1 = (k0b ? rp[5] : rp[1]) + __shfl_xor(k0b ? rp[1] : rp[5], 1);
      float s2 = (k0b ? rp[6] : rp[2]) + __shfl_xor(k0b ? rp[2] : rp[6], 1);
      float s3 = (k0b ? rp[7] : rp[3]) + __shfl_xor(k0b ? rp[3] : rp[7], 1);
      float t0 = (k1b ? s2 : s0) + __shfl_xor(k1b ? s0 : s2, 2);
      float t1 = (k1b ? s3 : s1) + __shfl_xor(k1b ? s1 : s3, 2);
      float u0 = (k2b ? t1 : t0) + __shfl_xor(k2b ? t0 : t1, 4);
      u0 += __shfl_xor(u0, 8);
      u0 += __shfl_xor(u0, 16);
      u0 += __shfl_xor(u0, 32);
      // my row's delta
      float dmine = 1.0f / fmaf(yl, u0, ymk[base_n + row0 + myr]);
      // broadcast back: lane holding row r is ((r&1)<<2) | (r&2) | ((r>>2)&1)
      #pragma unroll
      for (int r = 0; r < 8; ++r)
        dl[r] = __shfl(dmine, (((r & 1) << 2) | (r & 2) | ((r >> 2) & 1)));
    }
    // ---- sweep2: colpart = sum_r delta[r]*Q ----
    {
      float cp[8] = {0.f,0.f,0.f,0.f,0.f,0.f,0.f,0.f};
      #pragma unroll
      for (int r = 0; r < 8; ++r) {
        float d = dl[r];
        { u32 tw = Tp[r*4+0]; cp[0] = fmaf(bflo(tw),d,cp[0]); cp[1] = fmaf(bfhi(tw),d,cp[1]); }
        { u32 tw = Tp[r*4+1]; cp[2] = fmaf(bflo(tw),d,cp[2]); cp[3] = fmaf(bfhi(tw),d,cp[3]); }
        { u32 tw = Tp[r*4+2]; cp[4] = fmaf(bflo(tw),d,cp[4]); cp[5] = fmaf(bfhi(tw),d,cp[5]); }
        { u32 tw = Tp[r*4+3]; cp[6] = fmaf(bflo(tw),d,cp[6]); cp[7] = fmaf(bfhi(tw),d,cp[7]); }
      }
      // ---- write-once colsum: each wave its own slot, 1 sync ----
      float4 v0, v1;
      v0.x=cp[0]; v0.y=cp[1]; v0.z=cp[2]; v0.w=cp[3];
      v1.x=cp[4]; v1.y=cp[5]; v1.z=cp[6]; v1.w=cp[7];
      float4* dst = (float4*)&cpart[w][l << 3];
      dst[0] = v0; dst[1] = v1;
      __syncthreads();
    }
    if (tid < 512) {
      float s = 0.f;
      #pragma unroll
      for (int k = 0; k < 16; ++k) s += cpart[k][tid];
      __hip_atomic_store(&cp_b[(par << 11) + (p << 9) + tid], s, __ATOMIC_RELAXED, __HIP_MEMORY_SCOPE_AGENT);
    }
    batch_barrier(&cnt_b[it - 1], 4);
    if (tid < 512) {
      const float* basep = cp_b + (par << 11);
      float s = __hip_atomic_load(&basep[tid], __ATOMIC_RELAXED, __HIP_MEMORY_SCOPE_AGENT);
      s += __hip_atomic_load(&basep[512 + tid], __ATOMIC_RELAXED, __HIP_MEMORY_SCOPE_AGENT);
      s += __hip_atomic_load(&basep[1024 + tid], __ATOMIC_RELAXED, __HIP_MEMORY_SCOPE_AGENT);
      s += __hip_atomic_load(&basep[1536 + tid], __ATOMIC_RELAXED, __HIP_MEMORY_SCOPE_AGENT);
      sig[tid] = 1.0f / fmaf(xl, s, xmk[tid]);
    }
    __syncthreads();
    // ---- sweep3: T = Q * delta * sigma' ----
    {
      float sg[8];
      const float4* ps = (const float4*)&sig[l << 3];
      float4 s0v = ps[0], s1v = ps[1];
      sg[0]=s0v.x; sg[1]=s0v.y; sg[2]=s0v.z; sg[3]=s0v.w;
      sg[4]=s1v.x; sg[5]=s1v.y; sg[6]=s1v.z; sg[7]=s1v.w;
      #pragma unroll
      for (int r = 0; r < 8; ++r) {
        float d = dl[r];
        { u32 tw = Tp[r*4+0]; Tp[r*4+0] = pkbf(bflo(tw)*d*sg[0], bfhi(tw)*d*sg[1]); }
        { u32 tw = Tp[r*4+1]; Tp[r*4+1] = pkbf(bflo(tw)*d*sg[2], bfhi(tw)*d*sg[3]); }
        { u32 tw = Tp[r*4+2]; Tp[r*4+2] = pkbf(bflo(tw)*d*sg[4], bfhi(tw)*d*sg[5]); }
        { u32 tw = Tp[r*4+3]; Tp[r*4+3] = pkbf(bflo(tw)*d*sg[6], bfhi(tw)*d*sg[7]); }
      }
    }
  }

  // ---- final: partial dist = sum Ct2*T (masked: Ct2=3e4 but T=0 exactly) ----
  float accT = 0.f;
  #pragma unroll
  for (int r = 0; r < 8; ++r) {
    const uint4 cv = *(const uint4*)(Cb + (size_t)(row0 + r) * 512 + (l << 3));
    { u32 tw = Tp[r*4+0]; accT = fmaf(bflo(cv.x), bflo(tw), accT); accT = fmaf(bfhi(cv.x), bfhi(tw), accT); }
    { u32 tw = Tp[r*4+1]; accT = fmaf(bflo(cv.y), bflo(tw), accT); accT = fmaf(bfhi(cv.y), bfhi(tw), accT); }
    { u32 tw = Tp[r*4+2]; accT = fmaf(bflo(cv.z), bflo(tw), accT); accT = fmaf(bfhi(cv.z), bfhi(tw), accT); }
    { u32 tw = Tp[r*4+3]; accT = fmaf(bflo(cv.w), bflo(tw), accT); accT = fmaf(bfhi(cv.w), bfhi(tw), accT); }
  }
  #pragma unroll
  for (int off = 32; off; off >>= 1) accT += __shfl_xor(accT, off);
  if (l == 0) redw[w] = accT;
  __syncthreads();
  if (tid == 0) {
    float s = 0.f;
    #pragma unroll
    for (int ww = 0; ww < 16; ++ww) s += redw[ww];
    __hip_atomic_store(&fin_part[(b << 2) + p], s, __ATOMIC_RELAXED, __HIP_MEMORY_SCOPE_AGENT);
  }
  batch_barrier(&cnt_b[50], 4);
  if (p == 0 && tid == 0) {
    float s = 0.f;
    #pragma unroll
    for (int pp = 0; pp < 4; ++pp)
      s += __hip_atomic_load(&fin_part[(b << 2) + pp], __ATOMIC_RELAXED, __HIP_MEMORY_SCOPE_AGENT);
    ot[b] = s * 0.34657359f;  // beta * ln2  (Ct2 is in log2 units)
  }
}

// ---------------- finalize: out = sum_b (ot[b] - llh[b]) ----------------
__global__ __launch_bounds__(64) void k_finalize(const float* __restrict__ llh, const float* __restrict__ ot,
                                                 float* __restrict__ out) {
  int l = threadIdx.x;
  float v = ot[l] - llh[l];
  #pragma unroll
  for (int off = 32; off; off >>= 1) v += __shfl_down(v, off);
  if (l == 0) out[0] = v;
}

extern "C" void kernel_launch(void* const* d_in, const int* in_sizes, int n_in,
                              void* d_out, int out_size, void* d_ws, size_t ws_size,
                              hipStream_t stream) {
  const float* emis  = (const float*)d_in[0];
  const float* txt   = (const float*)d_in[1];
  const float* img   = (const float*)d_in[2];
  const float* startT= (const float*)d_in[3];
  const float* endT  = (const float*)d_in[4];
  const float* trans = (const float*)d_in[5];
  const int*  tags   = (const int*)d_in[6];
  const u8* cmask = (const u8*)d_in[7];
  const u8* xpad  = (const u8*)d_in[8];
  const u8* ypad  = (const u8*)d_in[9];
  char* wsb = (char*)d_ws;
  u16* xh  = (u16*)wsb;                          // 50331648 B
  u16* yh  = (u16*)(wsb + 50331648ll);           // 50331648 B
  u16* Ct2 = (u16*)(wsb + 100663296ll);          // 33554432 B
  float* ot    = (float*)(wsb + 134217728ll);    // 64
  float* llh   = ot + 64;                        // 64
  int*  flags  = (int*)(llh + 64);
  int*  gcount = (int*)(wsb + 134218752ll);      // 64*64 ints = 16384 B
  float* c_part= (float*)(wsb + 134235136ll);    // 64*2*4*512 f32 = 1 MB
  float* fin_part=(float*)(wsb + 135283712ll);   // 64*4 f32
  float* out = (float*)d_out;

  hipMemsetAsync(gcount, 0, 64 * 64 * sizeof(int), stream);
  hipLaunchKernelGGL(k_detect, dim3(1), dim3(1), 0, stream, (const u32*)cmask, flags);
  hipLaunchKernelGGL(k_normalize, dim3(16384), dim3(256), 0, stream, txt, img, xh, yh);
  hipLaunchKernelGGL(k_gemm_crf, dim3(1088), dim3(256), 0, stream, xh, yh, xpad, ypad, flags, Ct2,
                     emis, tags, cmask, startT, endT, trans, llh);
  hipLaunchKernelGGL(k_ipot_f8b, dim3(256), dim3(1024), 0, stream,
                     Ct2, xpad, ypad, flags, gcount, c_part, fin_part, ot);
  hipLaunchKernelGGL(k_finalize, dim3(1), dim3(64), 0, stream, llh, ot, out);
}